// Round 8
// baseline (485.573 us; speedup 1.0000x reference)
//
#include <hip/hip_runtime.h>
#include <hip/hip_fp16.h>

#define NROW 32768
#define DIM  256
#define NC   8192
#define CAP  16384                     // max rescued rows (expect ~3000)
#define MARGINF 0.375f                 // truncated-gap flag threshold (0.25 analysis + 0.125 trunc)
#define BIAS 512.0f                    // cheap-score bias: guarantees all cheap scores negative
#define AST 576                        // A' row: [hi 256 | ones 32 | lo 256 | pad 32] halves
#define BST 576                        // B' row: [hi 256 | ch 32   | lo 256 | pad 32] halves
#define LOSS_SCALE (1.0f / 8388608.0f)

typedef __attribute__((ext_vector_type(8))) _Float16 half8;
typedef __attribute__((ext_vector_type(4))) _Float16 half4;
typedef __attribute__((ext_vector_type(4))) float   floatx4;
typedef const __attribute__((address_space(1))) void* gas_p;
typedef __attribute__((address_space(3))) void*       las_p;

static __device__ __forceinline__ unsigned short f2hb(float f) {
    _Float16 h = (_Float16)f;
    unsigned short u;
    __builtin_memcpy(&u, &h, 2);
    return u;
}
static __device__ __forceinline__ unsigned umin_(unsigned a, unsigned b) { return a < b ? a : b; }
static __device__ __forceinline__ unsigned umax_(unsigned a, unsigned b) { return a > b ? a : b; }

// ======================= prep kernels (fast path) =======================

// rows -> norms + A' = [xhi | ones | xlo | pad] f16, row stride 576
__global__ void prep_a_k(const float* __restrict__ x, unsigned short* __restrict__ Ah,
                         float* __restrict__ norms) {
    int row  = blockIdx.x * 4 + (threadIdx.x >> 6);
    int lane = threadIdx.x & 63;
    const float4 v = ((const float4*)(x + (size_t)row * DIM))[lane];
    float s = v.x * v.x + v.y * v.y + v.z * v.z + v.w * v.w;
#pragma unroll
    for (int off = 32; off; off >>= 1) s += __shfl_down(s, off, 64);
    if (lane == 0) norms[row] = s;
    ushort4 hi4 = make_ushort4(f2hb(v.x), f2hb(v.y), f2hb(v.z), f2hb(v.w));
    ushort4 lo4 = make_ushort4(f2hb(v.x - (float)(_Float16)v.x),
                               f2hb(v.y - (float)(_Float16)v.y),
                               f2hb(v.z - (float)(_Float16)v.z),
                               f2hb(v.w - (float)(_Float16)v.w));
    unsigned short* rp = Ah + (size_t)row * AST;
    *(ushort4*)(rp + lane * 4)       = hi4;
    *(ushort4*)(rp + 288 + lane * 4) = lo4;
    if (lane < 8) {                    // ones block at 256..287: [1,1,0,...,0]
        ushort4 ob = make_ushort4(0, 0, 0, 0);
        if (lane == 0) { ob.x = 0x3C00; ob.y = 0x3C00; }   // f16 1.0
        *(ushort4*)(rp + 256 + lane * 4) = ob;
    }
}

// per-code: fp32 cHalf (exact, rescue) + ch block of B' at 256..287 (f16 pair, cheap)
__global__ void code_norms_k(const float* __restrict__ e, unsigned short* __restrict__ Bh,
                             float* __restrict__ cHalf) {
    int j = blockIdx.x * 256 + threadIdx.x;
    float s = 0.f;
    for (int d = 0; d < DIM; ++d) { float v = e[(size_t)d * NC + j]; s += v * v; }
    cHalf[j] = 0.5f * s;
    float t = -0.5f * s - BIAS;
    unsigned short hi = f2hb(t);
    _Float16 hf; __builtin_memcpy(&hf, &hi, 2);
    unsigned short lo = f2hb(t - (float)hf);
    unsigned short* p = Bh + (size_t)j * BST + 256;
    p[0] = hi; p[1] = lo;
    for (int k2 = 2; k2 < 32; ++k2) p[k2] = 0;
}

// e [dim][code] -> B' hi (at 0) / lo (at 288) sections, code-major, stride 576
__global__ void prep_b_k(const float* __restrict__ e, unsigned short* __restrict__ Bh) {
    __shared__ float t[32][33];
    int jb = blockIdx.x * 32, db = blockIdx.y * 32;
#pragma unroll
    for (int i = 0; i < 4; ++i)
        t[threadIdx.y + i * 8][threadIdx.x] =
            e[(size_t)(db + threadIdx.y + i * 8) * NC + jb + threadIdx.x];
    __syncthreads();
#pragma unroll
    for (int i = 0; i < 4; ++i) {
        int j = jb + threadIdx.y + i * 8;
        int d = db + threadIdx.x;
        float val = t[threadIdx.x][threadIdx.y + i * 8];
        Bh[(size_t)j * BST + d]       = f2hb(val);
        Bh[(size_t)j * BST + 288 + d] = f2hb(val - (float)(_Float16)val);
    }
}

// chunk -> (A half-offset, B half-offset); c is compile-time (unrolled loop)
template<bool RESCUE>
static __device__ __forceinline__ void chunk_off(int c, int& ac, int& bc) {
    if constexpr (RESCUE) {
        if (c < 8)       { ac = c * 32;              bc = c * 32; }          // xhi.ehi
        else if (c < 16) { ac = (c - 8) * 32;        bc = 288 + (c - 8) * 32; } // xhi.elo
        else             { ac = 288 + (c - 16) * 32; bc = (c - 16) * 32; }   // xlo.ehi
    } else {
        ac = c * 32; bc = c * 32;      // c=0..7 hi.hi, c=8 const (ones.ch)
    }
}

// ======================= templated GEMM+argmax kernel =======================
// Block tile 128x128, wave tile 64x64 (4x4 frags of 16x16x32 f16 MFMA).
// R8: contiguous-prefix layout (cheap touches bytes 0..575 of each 1152B row
// -> per-XCD B slice ~1.3MB, L2-resident since js = blockIdx&3 is constant
// per XCD) + unrolled inner c-loop (compile-time chunk offsets, R6 codegen)
// + prefetch-ahead (loop-top barrier waits chunk c's loads issued one step
// earlier; next chunk's loads in flight during compute; next jt's c=0 loads
// in flight during the epilogue). Buffer = global chunk parity (jt&1)^(c&1)
// for odd CHUNKS. Hazard: barrier's lgkmcnt(0) retires all prior ds_reads of
// the buffer being overwritten.

template<int CHUNKS, int JT, int JSB, bool RESCUE>
__global__ __launch_bounds__(256, 2) void vq_gemm_k(
    const unsigned short* __restrict__ Ah, const unsigned short* __restrict__ Bh,
    const float* __restrict__ cHalf,
    float* __restrict__ pv, int* __restrict__ pj, float* __restrict__ psv,
    const int* __restrict__ list, const int* __restrict__ cnt)
{
    __shared__ __align__(16) _Float16 As[2][4096];
    __shared__ __align__(16) _Float16 Bs[2][4096];

    const int tid  = threadIdx.x;
    const int js   = blockIdx.x & ((1 << JSB) - 1);
    const int rb   = blockIdx.x >> JSB;
    const int row0 = rb * 128, col0 = js * (JT * 128);
    const int lane = tid & 63, l15 = lane & 15, lq = lane >> 4;
    const int wave = tid >> 6;
    const int wrow = (wave >> 1) * 64, wcol = (wave & 1) * 64;
    const int sr = tid >> 2, sp = (tid & 3) * 8;   // staging: row, k-part

    int nact = 0;
    if constexpr (RESCUE) {
        nact = *cnt;
        if (row0 >= nact) return;
    }

    const unsigned short *Abase0, *Abase1;
    if constexpr (RESCUE) {
        int i0 = row0 + sr, i1 = i0 + 64;
        int r0 = (i0 < nact) ? list[i0] : 0;
        int r1 = (i1 < nact) ? list[i1] : 0;
        Abase0 = Ah + (size_t)r0 * AST + sp;
        Abase1 = Ah + (size_t)r1 * AST + sp;
    } else {
        Abase0 = Ah + (size_t)(row0 + sr) * AST + sp;
        Abase1 = Abase0 + 64 * AST;
    }

    // cheap state: packed keys; rescue state: float best
    unsigned k1[16], k2[16];
    float bvf[16]; int bjf[16];
#pragma unroll
    for (int s = 0; s < 16; ++s) {
        k1[s] = 0xFFFFFFFFu; k2[s] = 0xFFFFFFFFu;
        bvf[s] = -3.4e38f; bjf[s] = 0;
    }

    const floatx4 fzero = {0.0f, 0.0f, 0.0f, 0.0f};
    floatx4 acc[4][4];
#pragma unroll
    for (int rf = 0; rf < 4; ++rf)
#pragma unroll
        for (int cf = 0; cf < 4; ++cf) acc[rf][cf] = fzero;

    const unsigned short* Bb = Bh + (size_t)(col0 + sr) * BST + sp;

#define LOAD4(AC, BC, BUF, BBASE)                                                            \
    do {                                                                                     \
        _Float16* la_ = &As[(BUF)][tid * 8];                                                 \
        _Float16* lb_ = &Bs[(BUF)][tid * 8];                                                 \
        __builtin_amdgcn_global_load_lds((gas_p)(Abase0 + (AC)),            (las_p)la_,          16, 0, 0); \
        __builtin_amdgcn_global_load_lds((gas_p)(Abase1 + (AC)),            (las_p)(la_ + 2048), 16, 0, 0); \
        __builtin_amdgcn_global_load_lds((gas_p)((BBASE) + (BC)),           (las_p)lb_,          16, 0, 0); \
        __builtin_amdgcn_global_load_lds((gas_p)((BBASE) + 64 * BST + (BC)),(las_p)(lb_ + 2048), 16, 0, 0); \
    } while (0)

    LOAD4(0, 0, 0, Bb);                           // prologue: jt=0, c=0 -> buf 0

    for (int jt = 0; jt < JT; ++jt) {
        const int p = (CHUNKS & 1) ? (jt & 1) : 0;   // per-jt starting parity
#pragma unroll
        for (int c = 0; c < CHUNKS; ++c) {
            const int buf = (c & 1) ^ p;
            __syncthreads();                       // waits chunk c's loads (in flight since c-1)
            if (c + 1 < CHUNKS) {                  // prefetch next chunk into other buffer
                int an, bn;
                chunk_off<RESCUE>(c + 1, an, bn);
                LOAD4(an, bn, buf ^ 1, Bb);
            } else if (jt + 1 < JT) {              // prefetch next jt's chunk 0 (overlaps epilogue)
                LOAD4(0, 0, buf ^ 1, Bb + 128 * BST);
            }

            half8 af[4], bf[4];
#pragma unroll
            for (int rf = 0; rf < 4; ++rf)
                af[rf] = *(const half8*)&As[buf][(wrow + rf * 16 + l15) * 32 + lq * 8];
#pragma unroll
            for (int cf = 0; cf < 4; ++cf)
                bf[cf] = *(const half8*)&Bs[buf][(wcol + cf * 16 + l15) * 32 + lq * 8];
#pragma unroll
            for (int rf = 0; rf < 4; ++rf)
#pragma unroll
                for (int cf = 0; cf < 4; ++cf)
                    acc[rf][cf] = __builtin_amdgcn_mfma_f32_16x16x32_f16(
                        af[rf], bf[cf], acc[rf][cf], 0, 0, 0);

            if (c == CHUNKS - 1) {
                // ---- per-jt epilogue (next jt's c=0 loads in flight) ----
                if constexpr (RESCUE) {
                    const int colbase = col0 + jt * 128 + wcol;
#pragma unroll
                    for (int cf = 0; cf < 4; ++cf) {
                        const int col = colbase + cf * 16 + l15;
                        const float ch = cHalf[col];        // exact fp32 subtraction
#pragma unroll
                        for (int rf = 0; rf < 4; ++rf)
#pragma unroll
                            for (int r = 0; r < 4; ++r) {
                                float s = acc[rf][cf][r] - ch;
                                int slot = rf * 4 + r;
                                if (s > bvf[slot]) { bvf[slot] = s; bjf[slot] = col; }
                            }
                    }
                } else {
                    const unsigned colloc = (unsigned)(jt * 128 + wcol);
#pragma unroll
                    for (int cf = 0; cf < 4; ++cf) {
                        const unsigned colb = colloc + cf * 16 + l15;   // 11-bit within-split col
#pragma unroll
                        for (int rf = 0; rf < 4; ++rf)
#pragma unroll
                            for (int r = 0; r < 4; ++r) {
                                unsigned key = (__float_as_uint(acc[rf][cf][r]) & 0xFFFFF800u) | colb;
                                int slot = rf * 4 + r;
                                unsigned t = umax_(key, k1[slot]);
                                k1[slot] = umin_(k1[slot], key);
                                k2[slot] = umin_(k2[slot], t);
                            }
                    }
                }
#pragma unroll
                for (int rf = 0; rf < 4; ++rf)
#pragma unroll
                    for (int cf = 0; cf < 4; ++cf) acc[rf][cf] = fzero;
            }
        }
        Bb += 128 * BST;
    }
#undef LOAD4

    // ---- cross-lane merge over the 16 lanes of each row-group ----
#pragma unroll
    for (int st = 1; st < 16; st <<= 1) {
#pragma unroll
        for (int s = 0; s < 16; ++s) {
            if constexpr (RESCUE) {
                float v2 = __shfl_xor(bvf[s], st, 64);
                int   j2 = __shfl_xor(bjf[s], st, 64);
                if (v2 > bvf[s] || (v2 == bvf[s] && j2 < bjf[s])) { bvf[s] = v2; bjf[s] = j2; }
            } else {
                unsigned o1 = (unsigned)__shfl_xor((int)k1[s], st, 64);
                unsigned o2 = (unsigned)__shfl_xor((int)k2[s], st, 64);
                unsigned t = umax_(k1[s], o1);
                k1[s] = umin_(k1[s], o1);
                k2[s] = umin_(umin_(k2[s], o2), t);
            }
        }
    }

    // ---- merge the two column-half waves per row through LDS ----
    __syncthreads();
    if constexpr (RESCUE) {
        float* mv = (float*)&As[0][0];       // [128][2]
        int*   mj = (int*)&Bs[0][0];
        if (l15 == 0) {
#pragma unroll
            for (int rf = 0; rf < 4; ++rf)
#pragma unroll
                for (int r = 0; r < 4; ++r) {
                    int rloc = wrow + rf * 16 + lq * 4 + r;
                    int slot = rf * 4 + r;
                    mv[rloc * 2 + (wave & 1)] = bvf[slot];
                    mj[rloc * 2 + (wave & 1)] = bjf[slot];
                }
        }
        __syncthreads();
        if (tid < 128) {
            float v0 = mv[tid * 2], v1 = mv[tid * 2 + 1];
            int   j0 = mj[tid * 2], j1 = mj[tid * 2 + 1];
            bool take1 = (v1 > v0) || (v1 == v0 && j1 < j0);
            pv[(size_t)js * CAP + row0 + tid] = take1 ? v1 : v0;
            pj[(size_t)js * CAP + row0 + tid] = take1 ? j1 : j0;
        }
    } else {
        unsigned* mk1 = (unsigned*)&As[0][0];    // [128][2]
        unsigned* mk2 = (unsigned*)&Bs[0][0];
        if (l15 == 0) {
#pragma unroll
            for (int rf = 0; rf < 4; ++rf)
#pragma unroll
                for (int r = 0; r < 4; ++r) {
                    int rloc = wrow + rf * 16 + lq * 4 + r;
                    int slot = rf * 4 + r;
                    mk1[rloc * 2 + (wave & 1)] = k1[slot];
                    mk2[rloc * 2 + (wave & 1)] = k2[slot];
                }
        }
        __syncthreads();
        if (tid < 128) {
            unsigned a1 = mk1[tid * 2], b1 = mk1[tid * 2 + 1];
            unsigned a2 = mk2[tid * 2], b2 = mk2[tid * 2 + 1];
            unsigned m1 = umin_(a1, b1);
            unsigned m2 = umin_(umin_(a2, b2), umax_(a1, b1));
            pv[(size_t)js * NROW + row0 + tid] = __uint_as_float(m1 & 0xFFFFF800u);
            pj[(size_t)js * NROW + row0 + tid] = (int)(m1 & 2047u) + js * (JT * 128);
            psv[(size_t)js * NROW + row0 + tid] = __uint_as_float(m2 & 0xFFFFF800u);
        }
    }
}

// ======================= cheap reduce: merge splits, flag, gather =======================

__global__ void vq_reduce_k(const float* __restrict__ pv, const int* __restrict__ pj,
                            const float* __restrict__ psv,
                            const float* __restrict__ norms, const unsigned short* __restrict__ Bh,
                            float* __restrict__ qout, float* __restrict__ iout,
                            float* __restrict__ lout, int* __restrict__ list,
                            int* __restrict__ cnt)
{
    __shared__ int jbuf[64];
    const int row0 = blockIdx.x * 64;
    const int tid = threadIdx.x;
    if (tid < 64) {
        int row = row0 + tid;
        float bv = pv[row]; int bj = pj[row]; float sv = psv[row];
#pragma unroll
        for (int s = 1; s < 4; ++s) {
            float v = pv[(size_t)s * NROW + row];
            int   j = pj[(size_t)s * NROW + row];
            float s2 = psv[(size_t)s * NROW + row];
            bool better = (v > bv) || (v == bv && j < bj);
            float loseBest = better ? bv : v;
            sv = fmaxf(fmaxf(sv, s2), loseBest);
            if (better) { bv = v; bj = j; }
        }
        bool flagged = (bv - sv) < MARGINF;
        if (flagged) {
            int idx = atomicAdd(cnt, 1);
            if (idx < CAP) {
                list[idx] = row;
                jbuf[tid] = -1;            // rescue pass will write this row
            } else {
                flagged = false;           // overflow: accept cheap result
            }
        }
        float rl = 0.f;
        if (!flagged) {
            iout[row] = (float)bj;
            jbuf[tid] = bj;
            // stored bv = s_biased + eps, eps in [0, 0.125) (neg-float mantissa trunc): center
            rl = norms[row] - 2.0f * (bv + BIAS - 0.0625f);
        }
#pragma unroll
        for (int off = 32; off; off >>= 1) rl += __shfl_down(rl, off, 64);
        if (tid == 0) atomicAdd(lout, rl * LOSS_SCALE);
    }
    __syncthreads();
    const int lane = tid & 63;
    for (int r = tid >> 6; r < 64; r += 4) {
        int j = jbuf[r];
        if (j >= 0) {
            const _Float16* bp = (const _Float16*)Bh + (size_t)j * BST + lane * 4;
            half4 h = *(const half4*)bp;
            half4 l = *(const half4*)(bp + 288);
            float4 v;
            v.x = (float)h[0] + (float)l[0];
            v.y = (float)h[1] + (float)l[1];
            v.z = (float)h[2] + (float)l[2];
            v.w = (float)h[3] + (float)l[3];
            *(float4*)&qout[(size_t)(row0 + r) * DIM + lane * 4] = v;
        }
    }
}

// ======================= rescue reduce: merge 32 splits, finalize =======================

__global__ void vq_reduce2_k(const float* __restrict__ pv2, const int* __restrict__ pj2,
                             const int* __restrict__ list, const int* __restrict__ cnt,
                             const float* __restrict__ norms, const unsigned short* __restrict__ Bh,
                             float* __restrict__ qout, float* __restrict__ iout,
                             float* __restrict__ lout)
{
    __shared__ int rbuf[64], jb2[64];
    const int n = *cnt < CAP ? *cnt : CAP;
    const int i0 = blockIdx.x * 64;
    if (i0 >= n) return;
    const int tid = threadIdx.x;
    if (tid < 64) {
        int i = i0 + tid;
        float rl = 0.f;
        if (i < n) {
            float bv = pv2[i]; int bj = pj2[i];
#pragma unroll 4
            for (int s = 1; s < 32; ++s) {
                float v = pv2[(size_t)s * CAP + i];
                int   j = pj2[(size_t)s * CAP + i];
                if (v > bv || (v == bv && j < bj)) { bv = v; bj = j; }
            }
            int row = list[i];
            iout[row] = (float)bj;
            rbuf[tid] = row;
            jb2[tid]  = bj;
            rl = norms[row] - 2.0f * bv;   // precise unbiased score
        } else {
            rbuf[tid] = -1;
        }
#pragma unroll
        for (int off = 32; off; off >>= 1) rl += __shfl_down(rl, off, 64);
        if (tid == 0) atomicAdd(lout, rl * LOSS_SCALE);
    }
    __syncthreads();
    const int lane = tid & 63;
    for (int r = tid >> 6; r < 64; r += 4) {
        int row = rbuf[r];
        if (row >= 0) {
            const _Float16* bp = (const _Float16*)Bh + (size_t)jb2[r] * BST + lane * 4;
            half4 h = *(const half4*)bp;
            half4 l = *(const half4*)(bp + 288);
            float4 v;
            v.x = (float)h[0] + (float)l[0];
            v.y = (float)h[1] + (float)l[1];
            v.z = (float)h[2] + (float)l[2];
            v.w = (float)h[3] + (float)l[3];
            *(float4*)&qout[(size_t)row * DIM + lane * 4] = v;
        }
    }
}

// ======================= fallback fp32 path (round-1, known-good) =======================

__global__ void transpose_k(const float* __restrict__ e, float* __restrict__ eT) {
    __shared__ float t[32][33];
    int jb = blockIdx.x * 32, db = blockIdx.y * 32;
#pragma unroll
    for (int i = 0; i < 4; ++i)
        t[threadIdx.y + i * 8][threadIdx.x] =
            e[(size_t)(db + threadIdx.y + i * 8) * NC + jb + threadIdx.x];
    __syncthreads();
#pragma unroll
    for (int i = 0; i < 4; ++i)
        eT[(size_t)(jb + threadIdx.y + i * 8) * DIM + db + threadIdx.x] =
            t[threadIdx.x][threadIdx.y + i * 8];
}

__global__ void row_norms_k(const float* __restrict__ x, float* __restrict__ norms) {
    int row  = blockIdx.x * 4 + (threadIdx.x >> 6);
    int lane = threadIdx.x & 63;
    const float4 v = ((const float4*)(x + (size_t)row * DIM))[lane];
    float s = v.x * v.x + v.y * v.y + v.z * v.z + v.w * v.w;
#pragma unroll
    for (int off = 32; off; off >>= 1) s += __shfl_down(s, off, 64);
    if (lane == 0) norms[row] = s;
}

__global__ void code_norms_fb_k(const float* __restrict__ e, float* __restrict__ cHalf) {
    int j = blockIdx.x * 256 + threadIdx.x;
    float s = 0.f;
    for (int d = 0; d < DIM; ++d) { float v = e[(size_t)d * NC + j]; s += v * v; }
    cHalf[j] = 0.5f * s;
}

__global__ __launch_bounds__(256, 4) void vq_main_k(
    const float* __restrict__ x, const float* __restrict__ e,
    const float* __restrict__ eT, const float* __restrict__ norms,
    const float* __restrict__ cHalf, float* __restrict__ qout,
    float* __restrict__ iout, float* __restrict__ lout, int useT)
{
    __shared__ float  As[2][32 * 68];
    __shared__ float4 Bs[2][512];
    const int tid  = threadIdx.x;
    const int row0 = blockIdx.x * 64;
    const int ty = tid >> 4, tx = tid & 15;
    const int ar = tid >> 2, ak = (tid & 3) * 4;
    const int bk = tid >> 4, bj = tid & 15;
    float bestv[4]; int bestj[4];
#pragma unroll
    for (int i = 0; i < 4; ++i) { bestv[i] = -3.4e38f; bestj[i] = 0; }
    float acc[4][4];
    float4 pa0, pa1, pb0, pb1;
    {
        const float* xp = x + (size_t)(row0 + ar) * DIM + ak;
        pa0 = *(const float4*)xp;
        pa1 = *(const float4*)(xp + 16);
        const float* ep = e + (size_t)bk * NC + bj * 4;
        pb0 = *(const float4*)ep;
        pb1 = *(const float4*)(ep + 16 * NC);
    }
    int buf = 0;
    for (int c = 0; c < 1024; ++c) {
        const int kc = c & 7;
#pragma unroll
        for (int q = 0; q < 4; ++q) As[buf][(ak + q) * 68 + ar]      = ((const float*)&pa0)[q];
#pragma unroll
        for (int q = 0; q < 4; ++q) As[buf][(16 + ak + q) * 68 + ar] = ((const float*)&pa1)[q];
        Bs[buf][bk * 16 + bj]        = pb0;
        Bs[buf][(bk + 16) * 16 + bj] = pb1;
        __syncthreads();
        if (c + 1 < 1024) {
            int j0n  = ((c + 1) >> 3) * 64;
            int kk0n = ((c + 1) & 7) * 32;
            const float* xp = x + (size_t)(row0 + ar) * DIM + kk0n + ak;
            pa0 = *(const float4*)xp;
            pa1 = *(const float4*)(xp + 16);
            const float* ep = e + (size_t)(kk0n + bk) * NC + j0n + bj * 4;
            pb0 = *(const float4*)ep;
            pb1 = *(const float4*)(ep + 16 * NC);
        }
        if (kc == 0) {
#pragma unroll
            for (int i = 0; i < 4; ++i)
#pragma unroll
                for (int j = 0; j < 4; ++j) acc[i][j] = 0.f;
        }
#pragma unroll
        for (int k = 0; k < 32; ++k) {
            float4 a = *(const float4*)&As[buf][k * 68 + ty * 4];
            float4 b = *(const float4*)&Bs[buf][k * 16 + tx];
            acc[0][0] += a.x * b.x; acc[0][1] += a.x * b.y; acc[0][2] += a.x * b.z; acc[0][3] += a.x * b.w;
            acc[1][0] += a.y * b.x; acc[1][1] += a.y * b.y; acc[1][2] += a.y * b.z; acc[1][3] += a.y * b.w;
            acc[2][0] += a.z * b.x; acc[2][1] += a.z * b.y; acc[2][2] += a.z * b.z; acc[2][3] += a.z * b.w;
            acc[3][0] += a.w * b.x; acc[3][1] += a.w * b.y; acc[3][2] += a.w * b.z; acc[3][3] += a.w * b.w;
        }
        if (kc == 7) {
            int j0 = (c >> 3) * 64;
            float4 ch = *(const float4*)&cHalf[j0 + tx * 4];
            int jb0 = j0 + tx * 4;
#pragma unroll
            for (int i = 0; i < 4; ++i)
#pragma unroll
                for (int j = 0; j < 4; ++j) {
                    float s = acc[i][j] - ((const float*)&ch)[j];
                    if (s > bestv[i]) { bestv[i] = s; bestj[i] = jb0 + j; }
                }
        }
        buf ^= 1;
    }
    __syncthreads();
    float* redv   = &As[0][0];
    int*   redj   = (int*)&As[0][1024];
    int*   idxbuf = (int*)&As[1][0];
#pragma unroll
    for (int i = 0; i < 4; ++i) {
        int r = ty * 4 + i;
        redv[r * 16 + tx] = bestv[i];
        redj[r * 16 + tx] = bestj[i];
    }
    __syncthreads();
    if (tid < 64) {
        float bvv = redv[tid * 16];
        int   bj2 = redj[tid * 16];
#pragma unroll
        for (int t = 1; t < 16; ++t) {
            float v = redv[tid * 16 + t];
            int   j = redj[tid * 16 + t];
            if (v > bvv || (v == bvv && j < bj2)) { bvv = v; bj2 = j; }
        }
        iout[row0 + tid] = (float)bj2;
        idxbuf[tid] = bj2;
        float rl = norms[row0 + tid] - 2.0f * bvv;
#pragma unroll
        for (int off = 32; off; off >>= 1) rl += __shfl_down(rl, off, 64);
        if (tid == 0) atomicAdd(lout, rl * LOSS_SCALE);
    }
    __syncthreads();
    {
        const int rr = tid >> 6, lane = tid & 63;
        for (int r = rr; r < 64; r += 4) {
            int j = idxbuf[r];
            float4 v;
            if (useT) {
                v = *(const float4*)&eT[(size_t)j * DIM + lane * 4];
            } else {
                int d = lane * 4;
                v.x = e[(size_t)d * NC + j];
                v.y = e[(size_t)(d + 1) * NC + j];
                v.z = e[(size_t)(d + 2) * NC + j];
                v.w = e[(size_t)(d + 3) * NC + j];
            }
            *(float4*)&qout[(size_t)(row0 + r) * DIM + lane * 4] = v;
        }
    }
}

// ======================= launch =======================

extern "C" void kernel_launch(void* const* d_in, const int* in_sizes, int n_in,
                              void* d_out, int out_size, void* d_ws, size_t ws_size,
                              hipStream_t stream) {
    const float* x = (const float*)d_in[0];   // [32768, 256]
    const float* e = (const float*)d_in[1];   // [256, 8192]

    float* qout = (float*)d_out;
    float* iout = qout + (size_t)NROW * DIM;
    float* lout = iout + NROW;

    char* ws = (char*)d_ws;
    const size_t offAh    = 0;                    // 32768*576*2 = 37,748,736
    const size_t offBh    = offAh + 37748736;     //  8192*576*2 =  9,437,184
    const size_t offNorms = offBh + 9437184;      //    131,072
    const size_t offCH    = offNorms + 131072;    //     32,768 (fp32 cHalf, rescue)
    const size_t offPV    = offCH + 32768;        //    524,288 (4 splits x NROW)
    const size_t offPJ    = offPV + 524288;       //    524,288
    const size_t offPSV   = offPJ + 524288;       //    524,288
    const size_t offPV2   = offPSV + 524288;      //  2,097,152 (32 x CAP x 4)
    const size_t offPJ2   = offPV2 + 2097152;     //  2,097,152
    const size_t offList  = offPJ2 + 2097152;     //     65,536
    const size_t offCnt   = offList + 65536;      //        256
    const size_t needFast = offCnt + 256;         // ~53.2 MB (proven: >=55.7 MB available, R3/R4)

    hipMemsetAsync(lout, 0, sizeof(float), stream);

    if (ws_size >= needFast) {
        unsigned short* Ah = (unsigned short*)(ws + offAh);
        unsigned short* Bh = (unsigned short*)(ws + offBh);
        float* norms = (float*)(ws + offNorms);
        float* cHalf = (float*)(ws + offCH);
        float* pv    = (float*)(ws + offPV);
        int*   pj    = (int*)(ws + offPJ);
        float* psv   = (float*)(ws + offPSV);
        float* pv2   = (float*)(ws + offPV2);
        int*   pj2   = (int*)(ws + offPJ2);
        int*   list  = (int*)(ws + offList);
        int*   cnt   = (int*)(ws + offCnt);

        hipMemsetAsync(cnt, 0, sizeof(int), stream);
        prep_a_k<<<NROW / 4, 256, 0, stream>>>(x, Ah, norms);
        code_norms_k<<<NC / 256, 256, 0, stream>>>(e, Bh, cHalf);
        prep_b_k<<<dim3(NC / 32, DIM / 32), dim3(32, 8), 0, stream>>>(e, Bh);
        // cheap pass: K=256 hi.hi + folded (-0.5||e||^2 - BIAS); 4 col-splits of 2048
        vq_gemm_k<9, 16, 2, false><<<1024, 256, 0, stream>>>(
            Ah, Bh, cHalf, pv, pj, psv, nullptr, nullptr);
        // merge + flag + finalize non-flagged
        vq_reduce_k<<<NROW / 64, 256, 0, stream>>>(
            pv, pj, psv, norms, Bh, qout, iout, lout, list, cnt);
        // precise pass (K=768, exact fp32 cHalf) on flagged rows: 32 col-splits of 256
        vq_gemm_k<24, 2, 5, true><<<(CAP / 128) * 32, 256, 0, stream>>>(
            Ah, Bh, cHalf, pv2, pj2, nullptr, list, cnt);
        vq_reduce2_k<<<CAP / 64, 256, 0, stream>>>(
            pv2, pj2, list, cnt, norms, Bh, qout, iout, lout);
    } else {
        // round-1 fp32 fallback
        float* fws   = (float*)d_ws;
        float* norms = fws;
        float* cHalf = fws + NROW;
        float* eT    = fws + NROW + NC;
        size_t need_T = (size_t)(NROW + NC) * sizeof(float) + (size_t)NC * DIM * sizeof(float);
        int useT = (ws_size >= need_T) ? 1 : 0;
        row_norms_k<<<NROW / 4, 256, 0, stream>>>(x, norms);
        code_norms_fb_k<<<NC / 256, 256, 0, stream>>>(e, cHalf);
        if (useT)
            transpose_k<<<dim3(NC / 32, DIM / 32), dim3(32, 8), 0, stream>>>(e, eT);
        vq_main_k<<<NROW / 64, 256, 0, stream>>>(x, e, eT, norms, cHalf, qout, iout, lout, useT);
    }
}

// Round 9
// 419.465 us; speedup vs baseline: 1.1576x; 1.1576x over previous
//
#include <hip/hip_runtime.h>
#include <hip/hip_fp16.h>

#define NROW 32768
#define DIM  256
#define NC   8192
#define CAP  16384                     // max rescued rows (expect ~4400)
#define MARGINF 0.375f                 // truncated-gap flag threshold (0.25 analysis + 0.125 trunc)
#define BIAS 512.0f                    // cheap-score bias: guarantees all cheap scores negative
#define AST 576                        // A' row: [hi 256 | ones 32 | lo 256 | pad 32] halves
#define BST 576                        // B' row: [hi 256 | ch 32   | lo 256 | pad 32] halves
#define LOSS_SCALE (1.0f / 8388608.0f)

typedef __attribute__((ext_vector_type(8))) _Float16 half8;
typedef __attribute__((ext_vector_type(4))) _Float16 half4;
typedef __attribute__((ext_vector_type(4))) float   floatx4;
typedef const __attribute__((address_space(1))) void* gas_p;
typedef __attribute__((address_space(3))) void*       las_p;

static __device__ __forceinline__ unsigned short f2hb(float f) {
    _Float16 h = (_Float16)f;
    unsigned short u;
    __builtin_memcpy(&u, &h, 2);
    return u;
}
static __device__ __forceinline__ unsigned umin_(unsigned a, unsigned b) { return a < b ? a : b; }
static __device__ __forceinline__ unsigned umax_(unsigned a, unsigned b) { return a > b ? a : b; }

// ======================= prep kernels (fast path) =======================

__global__ void prep_a_k(const float* __restrict__ x, unsigned short* __restrict__ Ah,
                         float* __restrict__ norms) {
    int row  = blockIdx.x * 4 + (threadIdx.x >> 6);
    int lane = threadIdx.x & 63;
    const float4 v = ((const float4*)(x + (size_t)row * DIM))[lane];
    float s = v.x * v.x + v.y * v.y + v.z * v.z + v.w * v.w;
#pragma unroll
    for (int off = 32; off; off >>= 1) s += __shfl_down(s, off, 64);
    if (lane == 0) norms[row] = s;
    ushort4 hi4 = make_ushort4(f2hb(v.x), f2hb(v.y), f2hb(v.z), f2hb(v.w));
    ushort4 lo4 = make_ushort4(f2hb(v.x - (float)(_Float16)v.x),
                               f2hb(v.y - (float)(_Float16)v.y),
                               f2hb(v.z - (float)(_Float16)v.z),
                               f2hb(v.w - (float)(_Float16)v.w));
    unsigned short* rp = Ah + (size_t)row * AST;
    *(ushort4*)(rp + lane * 4)       = hi4;
    *(ushort4*)(rp + 288 + lane * 4) = lo4;
    if (lane < 8) {                    // ones block (legacy, unused by R9 cheap)
        ushort4 ob = make_ushort4(0, 0, 0, 0);
        if (lane == 0) { ob.x = 0x3C00; ob.y = 0x3C00; }
        *(ushort4*)(rp + 256 + lane * 4) = ob;
    }
}

__global__ void code_norms_k(const float* __restrict__ e, unsigned short* __restrict__ Bh,
                             float* __restrict__ cHalf) {
    int j = blockIdx.x * 256 + threadIdx.x;
    float s = 0.f;
    for (int d = 0; d < DIM; ++d) { float v = e[(size_t)d * NC + j]; s += v * v; }
    cHalf[j] = 0.5f * s;
    float t = -0.5f * s - BIAS;        // legacy ch block (unused by R9 cheap)
    unsigned short hi = f2hb(t);
    _Float16 hf; __builtin_memcpy(&hf, &hi, 2);
    unsigned short lo = f2hb(t - (float)hf);
    unsigned short* p = Bh + (size_t)j * BST + 256;
    p[0] = hi; p[1] = lo;
    for (int k2 = 2; k2 < 32; ++k2) p[k2] = 0;
}

__global__ void prep_b_k(const float* __restrict__ e, unsigned short* __restrict__ Bh) {
    __shared__ float t[32][33];
    int jb = blockIdx.x * 32, db = blockIdx.y * 32;
#pragma unroll
    for (int i = 0; i < 4; ++i)
        t[threadIdx.y + i * 8][threadIdx.x] =
            e[(size_t)(db + threadIdx.y + i * 8) * NC + jb + threadIdx.x];
    __syncthreads();
#pragma unroll
    for (int i = 0; i < 4; ++i) {
        int j = jb + threadIdx.y + i * 8;
        int d = db + threadIdx.x;
        float val = t[threadIdx.x][threadIdx.y + i * 8];
        Bh[(size_t)j * BST + d]       = f2hb(val);
        Bh[(size_t)j * BST + 288 + d] = f2hb(val - (float)(_Float16)val);
    }
}

// ======================= R9 cheap kernel: A LDS-resident =======================
// Block = 128 rows x 2048 cols (js 4-way). A-hi (64 KB) + cHalf+BIAS (8 KB)
// loaded to LDS ONCE; only B streams (16 KB/chunk, dbuf, 1-deep prefetch).
// jt = 8 tiles of 256 cols; 8 chunks each. Wave tile 64x128 (4x8 frags of
// 16x16x32 f16 MFMA) -> 32 MFMA per staged 16 KB (2x R8's ratio). Per-chunk
// MFMA ~620 cyc/SIMD > B L2-refill ~500 cyc: 1-deep prefetch + barrier OK.
// Epilogue: s = acc - (cHalf+BIAS) [fp32 LDS], branch-free uint-key top-2.

__global__ __launch_bounds__(256, 1) void vq_cheap_k(
    const unsigned short* __restrict__ Ah, const unsigned short* __restrict__ Bh,
    const float* __restrict__ cHalf,
    float* __restrict__ pv, int* __restrict__ pj, float* __restrict__ psv)
{
    __shared__ __align__(16) _Float16 Asl[8][4096];   // [chunk][row*32+k]  64 KB
    __shared__ __align__(16) _Float16 Bsl[2][8192];   // [buf][col*32+k]    32 KB
    __shared__ float chl[2048];                       //                     8 KB

    const int tid  = threadIdx.x;
    const int js   = blockIdx.x & 3;
    const int rb   = blockIdx.x >> 2;
    const int row0 = rb * 128, col0 = js * 2048;
    const int lane = tid & 63, l15 = lane & 15, lq = lane >> 4;
    const int wave = tid >> 6;
    const int wr = (wave >> 1) * 64;       // row offset: 0 / 64
    const int wc = (wave & 1) * 128;       // col offset: 0 / 128
    const int sr = tid >> 2, sp = (tid & 3) * 8;

    // ---- prologue: A-hi -> LDS (8 chunks x 2 row-halves), cHalf+BIAS -> LDS ----
    const unsigned short* Abase = Ah + (size_t)(row0 + sr) * AST + sp;
#pragma unroll
    for (int c = 0; c < 8; ++c) {
        __builtin_amdgcn_global_load_lds((gas_p)(Abase + c * 32),            (las_p)&Asl[c][tid * 8],        16, 0, 0);
        __builtin_amdgcn_global_load_lds((gas_p)(Abase + 64 * AST + c * 32), (las_p)&Asl[c][2048 + tid * 8], 16, 0, 0);
    }
    {
        const float4* cp = (const float4*)(cHalf + col0);
        float4 a = cp[tid * 2], b = cp[tid * 2 + 1];
        a.x += BIAS; a.y += BIAS; a.z += BIAS; a.w += BIAS;
        b.x += BIAS; b.y += BIAS; b.z += BIAS; b.w += BIAS;
        ((float4*)chl)[tid * 2]     = a;
        ((float4*)chl)[tid * 2 + 1] = b;
    }

#define LOADB(JT_, C_, BUF_)                                                                  \
    do {                                                                                      \
        const unsigned short* bb_ = Bh + (size_t)(col0 + (JT_) * 256 + sr) * BST + (C_) * 32 + sp; \
        _Float16* lb_ = &Bsl[(BUF_)][tid * 8];                                                \
        __builtin_amdgcn_global_load_lds((gas_p)(bb_),             (las_p)lb_,           16, 0, 0); \
        __builtin_amdgcn_global_load_lds((gas_p)(bb_ + 64 * BST),  (las_p)(lb_ + 2048),  16, 0, 0); \
        __builtin_amdgcn_global_load_lds((gas_p)(bb_ + 128 * BST), (las_p)(lb_ + 4096),  16, 0, 0); \
        __builtin_amdgcn_global_load_lds((gas_p)(bb_ + 192 * BST), (las_p)(lb_ + 6144),  16, 0, 0); \
    } while (0)

    unsigned k1[16], k2[16];
#pragma unroll
    for (int s = 0; s < 16; ++s) { k1[s] = 0xFFFFFFFFu; k2[s] = 0xFFFFFFFFu; }

    const floatx4 fzero = {0.0f, 0.0f, 0.0f, 0.0f};
    floatx4 acc[4][8];
#pragma unroll
    for (int rf = 0; rf < 4; ++rf)
#pragma unroll
        for (int cf = 0; cf < 8; ++cf) acc[rf][cf] = fzero;

    LOADB(0, 0, 0);

    for (int jt = 0; jt < 8; ++jt) {
#pragma unroll
        for (int c = 0; c < 8; ++c) {
            const int buf = c & 1;
            __syncthreads();                     // waits B chunk c (issued 1 step ago) (+A/chl first time)
            if (c < 7)           LOADB(jt, c + 1, buf ^ 1);
            else if (jt < 7)     LOADB(jt + 1, 0, buf ^ 1);

            half8 af[4], bf[8];
#pragma unroll
            for (int rf = 0; rf < 4; ++rf)
                af[rf] = *(const half8*)&Asl[c][(wr + rf * 16 + l15) * 32 + lq * 8];
#pragma unroll
            for (int cf = 0; cf < 8; ++cf)
                bf[cf] = *(const half8*)&Bsl[buf][(wc + cf * 16 + l15) * 32 + lq * 8];
#pragma unroll
            for (int rf = 0; rf < 4; ++rf)
#pragma unroll
                for (int cf = 0; cf < 8; ++cf)
                    acc[rf][cf] = __builtin_amdgcn_mfma_f32_16x16x32_f16(
                        af[rf], bf[cf], acc[rf][cf], 0, 0, 0);

            if (c == 7) {
                // ---- per-jt epilogue (next jt's chunk-0 loads in flight) ----
#pragma unroll
                for (int cf = 0; cf < 8; ++cf) {
                    const unsigned colb = (unsigned)(jt * 256 + wc + cf * 16 + l15); // 11-bit local col
                    const float ch = chl[colb];
#pragma unroll
                    for (int rf = 0; rf < 4; ++rf)
#pragma unroll
                        for (int r = 0; r < 4; ++r) {
                            float s = acc[rf][cf][r] - ch;
                            unsigned key = (__float_as_uint(s) & 0xFFFFF800u) | colb;
                            int slot = rf * 4 + r;
                            unsigned t = umax_(key, k1[slot]);
                            k1[slot] = umin_(k1[slot], key);
                            k2[slot] = umin_(k2[slot], t);
                        }
                }
#pragma unroll
                for (int rf = 0; rf < 4; ++rf)
#pragma unroll
                    for (int cf = 0; cf < 8; ++cf) acc[rf][cf] = fzero;
            }
        }
    }
#undef LOADB

    // ---- cross-lane merge over the 16 l15-lanes of each row-group ----
#pragma unroll
    for (int st = 1; st < 16; st <<= 1) {
#pragma unroll
        for (int s = 0; s < 16; ++s) {
            unsigned o1 = (unsigned)__shfl_xor((int)k1[s], st, 64);
            unsigned o2 = (unsigned)__shfl_xor((int)k2[s], st, 64);
            unsigned t = umax_(k1[s], o1);
            k1[s] = umin_(k1[s], o1);
            k2[s] = umin_(umin_(k2[s], o2), t);
        }
    }

    // ---- merge the two column-half waves per row through LDS ----
    __syncthreads();
    unsigned* mk1 = (unsigned*)&Asl[0][0];       // [128][2]
    unsigned* mk2 = (unsigned*)&Asl[1][0];
    if (l15 == 0) {
#pragma unroll
        for (int rf = 0; rf < 4; ++rf)
#pragma unroll
            for (int r = 0; r < 4; ++r) {
                int rloc = wr + rf * 16 + lq * 4 + r;
                int slot = rf * 4 + r;
                mk1[rloc * 2 + (wave & 1)] = k1[slot];
                mk2[rloc * 2 + (wave & 1)] = k2[slot];
            }
    }
    __syncthreads();
    if (tid < 128) {
        unsigned a1 = mk1[tid * 2], b1 = mk1[tid * 2 + 1];
        unsigned a2 = mk2[tid * 2], b2 = mk2[tid * 2 + 1];
        unsigned m1 = umin_(a1, b1);
        unsigned m2 = umin_(umin_(a2, b2), umax_(a1, b1));
        pv[(size_t)js * NROW + row0 + tid]  = __uint_as_float(m1 & 0xFFFFF800u);
        pj[(size_t)js * NROW + row0 + tid]  = (int)(m1 & 2047u) + js * 2048;
        psv[(size_t)js * NROW + row0 + tid] = __uint_as_float(m2 & 0xFFFFF800u);
    }
}

// ======================= rescue GEMM (R8-verified, unchanged) =======================

template<bool RESCUE>
static __device__ __forceinline__ void chunk_off(int c, int& ac, int& bc) {
    if constexpr (RESCUE) {
        if (c < 8)       { ac = c * 32;              bc = c * 32; }
        else if (c < 16) { ac = (c - 8) * 32;        bc = 288 + (c - 8) * 32; }
        else             { ac = 288 + (c - 16) * 32; bc = (c - 16) * 32; }
    } else {
        ac = c * 32; bc = c * 32;
    }
}

template<int CHUNKS, int JT, int JSB, bool RESCUE>
__global__ __launch_bounds__(256, 2) void vq_gemm_k(
    const unsigned short* __restrict__ Ah, const unsigned short* __restrict__ Bh,
    const float* __restrict__ cHalf,
    float* __restrict__ pv, int* __restrict__ pj, float* __restrict__ psv,
    const int* __restrict__ list, const int* __restrict__ cnt)
{
    __shared__ __align__(16) _Float16 As[2][4096];
    __shared__ __align__(16) _Float16 Bs[2][4096];

    const int tid  = threadIdx.x;
    const int js   = blockIdx.x & ((1 << JSB) - 1);
    const int rb   = blockIdx.x >> JSB;
    const int row0 = rb * 128, col0 = js * (JT * 128);
    const int lane = tid & 63, l15 = lane & 15, lq = lane >> 4;
    const int wave = tid >> 6;
    const int wrow = (wave >> 1) * 64, wcol = (wave & 1) * 64;
    const int sr = tid >> 2, sp = (tid & 3) * 8;

    int nact = 0;
    if constexpr (RESCUE) {
        nact = *cnt;
        if (row0 >= nact) return;
    }

    const unsigned short *Abase0, *Abase1;
    if constexpr (RESCUE) {
        int i0 = row0 + sr, i1 = i0 + 64;
        int r0 = (i0 < nact) ? list[i0] : 0;
        int r1 = (i1 < nact) ? list[i1] : 0;
        Abase0 = Ah + (size_t)r0 * AST + sp;
        Abase1 = Ah + (size_t)r1 * AST + sp;
    } else {
        Abase0 = Ah + (size_t)(row0 + sr) * AST + sp;
        Abase1 = Abase0 + 64 * AST;
    }

    unsigned k1[16], k2[16];
    float bvf[16]; int bjf[16];
#pragma unroll
    for (int s = 0; s < 16; ++s) {
        k1[s] = 0xFFFFFFFFu; k2[s] = 0xFFFFFFFFu;
        bvf[s] = -3.4e38f; bjf[s] = 0;
    }

    const floatx4 fzero = {0.0f, 0.0f, 0.0f, 0.0f};
    floatx4 acc[4][4];
#pragma unroll
    for (int rf = 0; rf < 4; ++rf)
#pragma unroll
        for (int cf = 0; cf < 4; ++cf) acc[rf][cf] = fzero;

    const unsigned short* Bb = Bh + (size_t)(col0 + sr) * BST + sp;

#define LOAD4(AC, BC, BUF, BBASE)                                                            \
    do {                                                                                     \
        _Float16* la_ = &As[(BUF)][tid * 8];                                                 \
        _Float16* lb_ = &Bs[(BUF)][tid * 8];                                                 \
        __builtin_amdgcn_global_load_lds((gas_p)(Abase0 + (AC)),            (las_p)la_,          16, 0, 0); \
        __builtin_amdgcn_global_load_lds((gas_p)(Abase1 + (AC)),            (las_p)(la_ + 2048), 16, 0, 0); \
        __builtin_amdgcn_global_load_lds((gas_p)((BBASE) + (BC)),           (las_p)lb_,          16, 0, 0); \
        __builtin_amdgcn_global_load_lds((gas_p)((BBASE) + 64 * BST + (BC)),(las_p)(lb_ + 2048), 16, 0, 0); \
    } while (0)

    LOAD4(0, 0, 0, Bb);

    for (int jt = 0; jt < JT; ++jt) {
        const int p = (CHUNKS & 1) ? (jt & 1) : 0;
#pragma unroll
        for (int c = 0; c < CHUNKS; ++c) {
            const int buf = (c & 1) ^ p;
            __syncthreads();
            if (c + 1 < CHUNKS) {
                int an, bn;
                chunk_off<RESCUE>(c + 1, an, bn);
                LOAD4(an, bn, buf ^ 1, Bb);
            } else if (jt + 1 < JT) {
                LOAD4(0, 0, buf ^ 1, Bb + 128 * BST);
            }

            half8 af[4], bf[4];
#pragma unroll
            for (int rf = 0; rf < 4; ++rf)
                af[rf] = *(const half8*)&As[buf][(wrow + rf * 16 + l15) * 32 + lq * 8];
#pragma unroll
            for (int cf = 0; cf < 4; ++cf)
                bf[cf] = *(const half8*)&Bs[buf][(wcol + cf * 16 + l15) * 32 + lq * 8];
#pragma unroll
            for (int rf = 0; rf < 4; ++rf)
#pragma unroll
                for (int cf = 0; cf < 4; ++cf)
                    acc[rf][cf] = __builtin_amdgcn_mfma_f32_16x16x32_f16(
                        af[rf], bf[cf], acc[rf][cf], 0, 0, 0);

            if (c == CHUNKS - 1) {
                if constexpr (RESCUE) {
                    const int colbase = col0 + jt * 128 + wcol;
#pragma unroll
                    for (int cf = 0; cf < 4; ++cf) {
                        const int col = colbase + cf * 16 + l15;
                        const float ch = cHalf[col];
#pragma unroll
                        for (int rf = 0; rf < 4; ++rf)
#pragma unroll
                            for (int r = 0; r < 4; ++r) {
                                float s = acc[rf][cf][r] - ch;
                                int slot = rf * 4 + r;
                                if (s > bvf[slot]) { bvf[slot] = s; bjf[slot] = col; }
                            }
                    }
                } else {
                    const unsigned colloc = (unsigned)(jt * 128 + wcol);
#pragma unroll
                    for (int cf = 0; cf < 4; ++cf) {
                        const unsigned colb = colloc + cf * 16 + l15;
#pragma unroll
                        for (int rf = 0; rf < 4; ++rf)
#pragma unroll
                            for (int r = 0; r < 4; ++r) {
                                unsigned key = (__float_as_uint(acc[rf][cf][r]) & 0xFFFFF800u) | colb;
                                int slot = rf * 4 + r;
                                unsigned t = umax_(key, k1[slot]);
                                k1[slot] = umin_(k1[slot], key);
                                k2[slot] = umin_(k2[slot], t);
                            }
                    }
                }
#pragma unroll
                for (int rf = 0; rf < 4; ++rf)
#pragma unroll
                    for (int cf = 0; cf < 4; ++cf) acc[rf][cf] = fzero;
            }
        }
        Bb += 128 * BST;
    }
#undef LOAD4

#pragma unroll
    for (int st = 1; st < 16; st <<= 1) {
#pragma unroll
        for (int s = 0; s < 16; ++s) {
            if constexpr (RESCUE) {
                float v2 = __shfl_xor(bvf[s], st, 64);
                int   j2 = __shfl_xor(bjf[s], st, 64);
                if (v2 > bvf[s] || (v2 == bvf[s] && j2 < bjf[s])) { bvf[s] = v2; bjf[s] = j2; }
            } else {
                unsigned o1 = (unsigned)__shfl_xor((int)k1[s], st, 64);
                unsigned o2 = (unsigned)__shfl_xor((int)k2[s], st, 64);
                unsigned t = umax_(k1[s], o1);
                k1[s] = umin_(k1[s], o1);
                k2[s] = umin_(umin_(k2[s], o2), t);
            }
        }
    }

    __syncthreads();
    if constexpr (RESCUE) {
        float* mv = (float*)&As[0][0];
        int*   mj = (int*)&Bs[0][0];
        if (l15 == 0) {
#pragma unroll
            for (int rf = 0; rf < 4; ++rf)
#pragma unroll
                for (int r = 0; r < 4; ++r) {
                    int rloc = wrow + rf * 16 + lq * 4 + r;
                    int slot = rf * 4 + r;
                    mv[rloc * 2 + (wave & 1)] = bvf[slot];
                    mj[rloc * 2 + (wave & 1)] = bjf[slot];
                }
        }
        __syncthreads();
        if (tid < 128) {
            float v0 = mv[tid * 2], v1 = mv[tid * 2 + 1];
            int   j0 = mj[tid * 2], j1 = mj[tid * 2 + 1];
            bool take1 = (v1 > v0) || (v1 == v0 && j1 < j0);
            pv[(size_t)js * CAP + row0 + tid] = take1 ? v1 : v0;
            pj[(size_t)js * CAP + row0 + tid] = take1 ? j1 : j0;
        }
    } else {
        unsigned* mk1 = (unsigned*)&As[0][0];
        unsigned* mk2 = (unsigned*)&Bs[0][0];
        if (l15 == 0) {
#pragma unroll
            for (int rf = 0; rf < 4; ++rf)
#pragma unroll
                for (int r = 0; r < 4; ++r) {
                    int rloc = wrow + rf * 16 + lq * 4 + r;
                    int slot = rf * 4 + r;
                    mk1[rloc * 2 + (wave & 1)] = k1[slot];
                    mk2[rloc * 2 + (wave & 1)] = k2[slot];
                }
        }
        __syncthreads();
        if (tid < 128) {
            unsigned a1 = mk1[tid * 2], b1 = mk1[tid * 2 + 1];
            unsigned a2 = mk2[tid * 2], b2 = mk2[tid * 2 + 1];
            unsigned m1 = umin_(a1, b1);
            unsigned m2 = umin_(umin_(a2, b2), umax_(a1, b1));
            pv[(size_t)js * NROW + row0 + tid] = __uint_as_float(m1 & 0xFFFFF800u);
            pj[(size_t)js * NROW + row0 + tid] = (int)(m1 & 2047u) + js * (JT * 128);
            psv[(size_t)js * NROW + row0 + tid] = __uint_as_float(m2 & 0xFFFFF800u);
        }
    }
}

// ======================= cheap reduce: merge splits, flag, gather =======================

__global__ void vq_reduce_k(const float* __restrict__ pv, const int* __restrict__ pj,
                            const float* __restrict__ psv,
                            const float* __restrict__ norms, const unsigned short* __restrict__ Bh,
                            float* __restrict__ qout, float* __restrict__ iout,
                            float* __restrict__ lout, int* __restrict__ list,
                            int* __restrict__ cnt)
{
    __shared__ int jbuf[64];
    const int row0 = blockIdx.x * 64;
    const int tid = threadIdx.x;
    if (tid < 64) {
        int row = row0 + tid;
        float bv = pv[row]; int bj = pj[row]; float sv = psv[row];
#pragma unroll
        for (int s = 1; s < 4; ++s) {
            float v = pv[(size_t)s * NROW + row];
            int   j = pj[(size_t)s * NROW + row];
            float s2 = psv[(size_t)s * NROW + row];
            bool better = (v > bv) || (v == bv && j < bj);
            float loseBest = better ? bv : v;
            sv = fmaxf(fmaxf(sv, s2), loseBest);
            if (better) { bv = v; bj = j; }
        }
        bool flagged = (bv - sv) < MARGINF;
        if (flagged) {
            int idx = atomicAdd(cnt, 1);
            if (idx < CAP) {
                list[idx] = row;
                jbuf[tid] = -1;
            } else {
                flagged = false;
            }
        }
        float rl = 0.f;
        if (!flagged) {
            iout[row] = (float)bj;
            jbuf[tid] = bj;
            rl = norms[row] - 2.0f * (bv + BIAS - 0.0625f);
        }
#pragma unroll
        for (int off = 32; off; off >>= 1) rl += __shfl_down(rl, off, 64);
        if (tid == 0) atomicAdd(lout, rl * LOSS_SCALE);
    }
    __syncthreads();
    const int lane = tid & 63;
    for (int r = tid >> 6; r < 64; r += 4) {
        int j = jbuf[r];
        if (j >= 0) {
            const _Float16* bp = (const _Float16*)Bh + (size_t)j * BST + lane * 4;
            half4 h = *(const half4*)bp;
            half4 l = *(const half4*)(bp + 288);
            float4 v;
            v.x = (float)h[0] + (float)l[0];
            v.y = (float)h[1] + (float)l[1];
            v.z = (float)h[2] + (float)l[2];
            v.w = (float)h[3] + (float)l[3];
            *(float4*)&qout[(size_t)(row0 + r) * DIM + lane * 4] = v;
        }
    }
}

// ======================= rescue reduce: merge 32 splits, finalize =======================

__global__ void vq_reduce2_k(const float* __restrict__ pv2, const int* __restrict__ pj2,
                             const int* __restrict__ list, const int* __restrict__ cnt,
                             const float* __restrict__ norms, const unsigned short* __restrict__ Bh,
                             float* __restrict__ qout, float* __restrict__ iout,
                             float* __restrict__ lout)
{
    __shared__ int rbuf[64], jb2[64];
    const int n = *cnt < CAP ? *cnt : CAP;
    const int i0 = blockIdx.x * 64;
    if (i0 >= n) return;
    const int tid = threadIdx.x;
    if (tid < 64) {
        int i = i0 + tid;
        float rl = 0.f;
        if (i < n) {
            float bv = pv2[i]; int bj = pj2[i];
#pragma unroll 4
            for (int s = 1; s < 32; ++s) {
                float v = pv2[(size_t)s * CAP + i];
                int   j = pj2[(size_t)s * CAP + i];
                if (v > bv || (v == bv && j < bj)) { bv = v; bj = j; }
            }
            int row = list[i];
            iout[row] = (float)bj;
            rbuf[tid] = row;
            jb2[tid]  = bj;
            rl = norms[row] - 2.0f * bv;
        } else {
            rbuf[tid] = -1;
        }
#pragma unroll
        for (int off = 32; off; off >>= 1) rl += __shfl_down(rl, off, 64);
        if (tid == 0) atomicAdd(lout, rl * LOSS_SCALE);
    }
    __syncthreads();
    const int lane = tid & 63;
    for (int r = tid >> 6; r < 64; r += 4) {
        int row = rbuf[r];
        if (row >= 0) {
            const _Float16* bp = (const _Float16*)Bh + (size_t)jb2[r] * BST + lane * 4;
            half4 h = *(const half4*)bp;
            half4 l = *(const half4*)(bp + 288);
            float4 v;
            v.x = (float)h[0] + (float)l[0];
            v.y = (float)h[1] + (float)l[1];
            v.z = (float)h[2] + (float)l[2];
            v.w = (float)h[3] + (float)l[3];
            *(float4*)&qout[(size_t)row * DIM + lane * 4] = v;
        }
    }
}

// ======================= fallback fp32 path (round-1, known-good) =======================

__global__ void transpose_k(const float* __restrict__ e, float* __restrict__ eT) {
    __shared__ float t[32][33];
    int jb = blockIdx.x * 32, db = blockIdx.y * 32;
#pragma unroll
    for (int i = 0; i < 4; ++i)
        t[threadIdx.y + i * 8][threadIdx.x] =
            e[(size_t)(db + threadIdx.y + i * 8) * NC + jb + threadIdx.x];
    __syncthreads();
#pragma unroll
    for (int i = 0; i < 4; ++i)
        eT[(size_t)(jb + threadIdx.y + i * 8) * DIM + db + threadIdx.x] =
            t[threadIdx.x][threadIdx.y + i * 8];
}

__global__ void row_norms_k(const float* __restrict__ x, float* __restrict__ norms) {
    int row  = blockIdx.x * 4 + (threadIdx.x >> 6);
    int lane = threadIdx.x & 63;
    const float4 v = ((const float4*)(x + (size_t)row * DIM))[lane];
    float s = v.x * v.x + v.y * v.y + v.z * v.z + v.w * v.w;
#pragma unroll
    for (int off = 32; off; off >>= 1) s += __shfl_down(s, off, 64);
    if (lane == 0) norms[row] = s;
}

__global__ void code_norms_fb_k(const float* __restrict__ e, float* __restrict__ cHalf) {
    int j = blockIdx.x * 256 + threadIdx.x;
    float s = 0.f;
    for (int d = 0; d < DIM; ++d) { float v = e[(size_t)d * NC + j]; s += v * v; }
    cHalf[j] = 0.5f * s;
}

__global__ __launch_bounds__(256, 4) void vq_main_k(
    const float* __restrict__ x, const float* __restrict__ e,
    const float* __restrict__ eT, const float* __restrict__ norms,
    const float* __restrict__ cHalf, float* __restrict__ qout,
    float* __restrict__ iout, float* __restrict__ lout, int useT)
{
    __shared__ float  As[2][32 * 68];
    __shared__ float4 Bs[2][512];
    const int tid  = threadIdx.x;
    const int row0 = blockIdx.x * 64;
    const int ty = tid >> 4, tx = tid & 15;
    const int ar = tid >> 2, ak = (tid & 3) * 4;
    const int bk = tid >> 4, bj = tid & 15;
    float bestv[4]; int bestj[4];
#pragma unroll
    for (int i = 0; i < 4; ++i) { bestv[i] = -3.4e38f; bestj[i] = 0; }
    float acc[4][4];
    float4 pa0, pa1, pb0, pb1;
    {
        const float* xp = x + (size_t)(row0 + ar) * DIM + ak;
        pa0 = *(const float4*)xp;
        pa1 = *(const float4*)(xp + 16);
        const float* ep = e + (size_t)bk * NC + bj * 4;
        pb0 = *(const float4*)ep;
        pb1 = *(const float4*)(ep + 16 * NC);
    }
    int buf = 0;
    for (int c = 0; c < 1024; ++c) {
        const int kc = c & 7;
#pragma unroll
        for (int q = 0; q < 4; ++q) As[buf][(ak + q) * 68 + ar]      = ((const float*)&pa0)[q];
#pragma unroll
        for (int q = 0; q < 4; ++q) As[buf][(16 + ak + q) * 68 + ar] = ((const float*)&pa1)[q];
        Bs[buf][bk * 16 + bj]        = pb0;
        Bs[buf][(bk + 16) * 16 + bj] = pb1;
        __syncthreads();
        if (c + 1 < 1024) {
            int j0n  = ((c + 1) >> 3) * 64;
            int kk0n = ((c + 1) & 7) * 32;
            const float* xp = x + (size_t)(row0 + ar) * DIM + kk0n + ak;
            pa0 = *(const float4*)xp;
            pa1 = *(const float4*)(xp + 16);
            const float* ep = e + (size_t)(kk0n + bk) * NC + j0n + bj * 4;
            pb0 = *(const float4*)ep;
            pb1 = *(const float4*)(ep + 16 * NC);
        }
        if (kc == 0) {
#pragma unroll
            for (int i = 0; i < 4; ++i)
#pragma unroll
                for (int j = 0; j < 4; ++j) acc[i][j] = 0.f;
        }
#pragma unroll
        for (int k = 0; k < 32; ++k) {
            float4 a = *(const float4*)&As[buf][k * 68 + ty * 4];
            float4 b = *(const float4*)&Bs[buf][k * 16 + tx];
            acc[0][0] += a.x * b.x; acc[0][1] += a.x * b.y; acc[0][2] += a.x * b.z; acc[0][3] += a.x * b.w;
            acc[1][0] += a.y * b.x; acc[1][1] += a.y * b.y; acc[1][2] += a.y * b.z; acc[1][3] += a.y * b.w;
            acc[2][0] += a.z * b.x; acc[2][1] += a.z * b.y; acc[2][2] += a.z * b.z; acc[2][3] += a.z * b.w;
            acc[3][0] += a.w * b.x; acc[3][1] += a.w * b.y; acc[3][2] += a.w * b.z; acc[3][3] += a.w * b.w;
        }
        if (kc == 7) {
            int j0 = (c >> 3) * 64;
            float4 ch = *(const float4*)&cHalf[j0 + tx * 4];
            int jb0 = j0 + tx * 4;
#pragma unroll
            for (int i = 0; i < 4; ++i)
#pragma unroll
                for (int j = 0; j < 4; ++j) {
                    float s = acc[i][j] - ((const float*)&ch)[j];
                    if (s > bestv[i]) { bestv[i] = s; bestj[i] = jb0 + j; }
                }
        }
        buf ^= 1;
    }
    __syncthreads();
    float* redv   = &As[0][0];
    int*   redj   = (int*)&As[0][1024];
    int*   idxbuf = (int*)&As[1][0];
#pragma unroll
    for (int i = 0; i < 4; ++i) {
        int r = ty * 4 + i;
        redv[r * 16 + tx] = bestv[i];
        redj[r * 16 + tx] = bestj[i];
    }
    __syncthreads();
    if (tid < 64) {
        float bvv = redv[tid * 16];
        int   bj2 = redj[tid * 16];
#pragma unroll
        for (int t = 1; t < 16; ++t) {
            float v = redv[tid * 16 + t];
            int   j = redj[tid * 16 + t];
            if (v > bvv || (v == bvv && j < bj2)) { bvv = v; bj2 = j; }
        }
        iout[row0 + tid] = (float)bj2;
        idxbuf[tid] = bj2;
        float rl = norms[row0 + tid] - 2.0f * bvv;
#pragma unroll
        for (int off = 32; off; off >>= 1) rl += __shfl_down(rl, off, 64);
        if (tid == 0) atomicAdd(lout, rl * LOSS_SCALE);
    }
    __syncthreads();
    {
        const int rr = tid >> 6, lane = tid & 63;
        for (int r = rr; r < 64; r += 4) {
            int j = idxbuf[r];
            float4 v;
            if (useT) {
                v = *(const float4*)&eT[(size_t)j * DIM + lane * 4];
            } else {
                int d = lane * 4;
                v.x = e[(size_t)d * NC + j];
                v.y = e[(size_t)(d + 1) * NC + j];
                v.z = e[(size_t)(d + 2) * NC + j];
                v.w = e[(size_t)(d + 3) * NC + j];
            }
            *(float4*)&qout[(size_t)(row0 + r) * DIM + lane * 4] = v;
        }
    }
}

// ======================= launch =======================

extern "C" void kernel_launch(void* const* d_in, const int* in_sizes, int n_in,
                              void* d_out, int out_size, void* d_ws, size_t ws_size,
                              hipStream_t stream) {
    const float* x = (const float*)d_in[0];   // [32768, 256]
    const float* e = (const float*)d_in[1];   // [256, 8192]

    float* qout = (float*)d_out;
    float* iout = qout + (size_t)NROW * DIM;
    float* lout = iout + NROW;

    char* ws = (char*)d_ws;
    const size_t offAh    = 0;                    // 32768*576*2 = 37,748,736
    const size_t offBh    = offAh + 37748736;     //  8192*576*2 =  9,437,184
    const size_t offNorms = offBh + 9437184;      //    131,072
    const size_t offCH    = offNorms + 131072;    //     32,768
    const size_t offPV    = offCH + 32768;        //    524,288
    const size_t offPJ    = offPV + 524288;       //    524,288
    const size_t offPSV   = offPJ + 524288;       //    524,288
    const size_t offPV2   = offPSV + 524288;      //  2,097,152
    const size_t offPJ2   = offPV2 + 2097152;     //  2,097,152
    const size_t offList  = offPJ2 + 2097152;     //     65,536
    const size_t offCnt   = offList + 65536;      //        256
    const size_t needFast = offCnt + 256;         // ~53.2 MB (proven: >=55.7 MB available)

    hipMemsetAsync(lout, 0, sizeof(float), stream);

    if (ws_size >= needFast) {
        unsigned short* Ah = (unsigned short*)(ws + offAh);
        unsigned short* Bh = (unsigned short*)(ws + offBh);
        float* norms = (float*)(ws + offNorms);
        float* cHalf = (float*)(ws + offCH);
        float* pv    = (float*)(ws + offPV);
        int*   pj    = (int*)(ws + offPJ);
        float* psv   = (float*)(ws + offPSV);
        float* pv2   = (float*)(ws + offPV2);
        int*   pj2   = (int*)(ws + offPJ2);
        int*   list  = (int*)(ws + offList);
        int*   cnt   = (int*)(ws + offCnt);

        hipMemsetAsync(cnt, 0, sizeof(int), stream);
        prep_a_k<<<NROW / 4, 256, 0, stream>>>(x, Ah, norms);
        code_norms_k<<<NC / 256, 256, 0, stream>>>(e, Bh, cHalf);
        prep_b_k<<<dim3(NC / 32, DIM / 32), dim3(32, 8), 0, stream>>>(e, Bh);
        // cheap pass (R9): A-resident LDS, K=256 hi.hi, fp32 cHalf+BIAS epilogue
        vq_cheap_k<<<1024, 256, 0, stream>>>(Ah, Bh, cHalf, pv, pj, psv);
        // merge + flag + finalize non-flagged
        vq_reduce_k<<<NROW / 64, 256, 0, stream>>>(
            pv, pj, psv, norms, Bh, qout, iout, lout, list, cnt);
        // precise pass (K=768, exact fp32 cHalf) on flagged rows: 32 col-splits of 256
        vq_gemm_k<24, 2, 5, true><<<(CAP / 128) * 32, 256, 0, stream>>>(
            Ah, Bh, cHalf, pv2, pj2, nullptr, list, cnt);
        vq_reduce2_k<<<CAP / 64, 256, 0, stream>>>(
            pv2, pj2, list, cnt, norms, Bh, qout, iout, lout);
    } else {
        // round-1 fp32 fallback
        float* fws   = (float*)d_ws;
        float* norms = fws;
        float* cHalf = fws + NROW;
        float* eT    = fws + NROW + NC;
        size_t need_T = (size_t)(NROW + NC) * sizeof(float) + (size_t)NC * DIM * sizeof(float);
        int useT = (ws_size >= need_T) ? 1 : 0;
        row_norms_k<<<NROW / 4, 256, 0, stream>>>(x, norms);
        code_norms_fb_k<<<NC / 256, 256, 0, stream>>>(e, cHalf);
        if (useT)
            transpose_k<<<dim3(NC / 32, DIM / 32), dim3(32, 8), 0, stream>>>(e, eT);
        vq_main_k<<<NROW / 64, 256, 0, stream>>>(x, e, eT, norms, cHalf, qout, iout, lout, useT);
    }
}

// Round 10
// 362.275 us; speedup vs baseline: 1.3403x; 1.1579x over previous
//
#include <hip/hip_runtime.h>
#include <hip/hip_fp16.h>

#define NROW 32768
#define DIM  256
#define NC   8192
#define CAP  16384                     // max rescued rows (expect ~2500)
#define MARGINF 0.25f                  // flag threshold: not-flagged => true cheap gap >= 0.125
#define BIAS 512.0f                    // cheap-score bias: guarantees all cheap scores negative
#define AST 576                        // A' row: [hi 256 | ones 32 | lo 256 | pad 32] halves
#define BST 576                        // B' row: [hi 256 | ch 32   | lo 256 | pad 32] halves
#define LOSS_SCALE (1.0f / 8388608.0f)

typedef __attribute__((ext_vector_type(8))) _Float16 half8;
typedef __attribute__((ext_vector_type(4))) _Float16 half4;
typedef __attribute__((ext_vector_type(4))) float   floatx4;
typedef const __attribute__((address_space(1))) void* gas_p;
typedef __attribute__((address_space(3))) void*       las_p;

static __device__ __forceinline__ unsigned short f2hb(float f) {
    _Float16 h = (_Float16)f;
    unsigned short u;
    __builtin_memcpy(&u, &h, 2);
    return u;
}
static __device__ __forceinline__ unsigned umin_(unsigned a, unsigned b) { return a < b ? a : b; }
static __device__ __forceinline__ unsigned umax_(unsigned a, unsigned b) { return a > b ? a : b; }

// ======================= prep kernels (fast path) =======================

__global__ void prep_a_k(const float* __restrict__ x, unsigned short* __restrict__ Ah,
                         float* __restrict__ norms) {
    int row  = blockIdx.x * 4 + (threadIdx.x >> 6);
    int lane = threadIdx.x & 63;
    const float4 v = ((const float4*)(x + (size_t)row * DIM))[lane];
    float s = v.x * v.x + v.y * v.y + v.z * v.z + v.w * v.w;
#pragma unroll
    for (int off = 32; off; off >>= 1) s += __shfl_down(s, off, 64);
    if (lane == 0) norms[row] = s;
    ushort4 hi4 = make_ushort4(f2hb(v.x), f2hb(v.y), f2hb(v.z), f2hb(v.w));
    ushort4 lo4 = make_ushort4(f2hb(v.x - (float)(_Float16)v.x),
                               f2hb(v.y - (float)(_Float16)v.y),
                               f2hb(v.z - (float)(_Float16)v.z),
                               f2hb(v.w - (float)(_Float16)v.w));
    unsigned short* rp = Ah + (size_t)row * AST;
    *(ushort4*)(rp + lane * 4)       = hi4;
    *(ushort4*)(rp + 288 + lane * 4) = lo4;
    if (lane < 8) {                    // legacy ones block (unused by R10 cheap)
        ushort4 ob = make_ushort4(0, 0, 0, 0);
        if (lane == 0) { ob.x = 0x3C00; ob.y = 0x3C00; }
        *(ushort4*)(rp + 256 + lane * 4) = ob;
    }
}

__global__ void code_norms_k(const float* __restrict__ e, unsigned short* __restrict__ Bh,
                             float* __restrict__ cHalf) {
    int j = blockIdx.x * 256 + threadIdx.x;
    float s = 0.f;
    for (int d = 0; d < DIM; ++d) { float v = e[(size_t)d * NC + j]; s += v * v; }
    cHalf[j] = 0.5f * s;
    float t = -0.5f * s - BIAS;        // legacy ch block (unused by R10 cheap)
    unsigned short hi = f2hb(t);
    _Float16 hf; __builtin_memcpy(&hf, &hi, 2);
    unsigned short lo = f2hb(t - (float)hf);
    unsigned short* p = Bh + (size_t)j * BST + 256;
    p[0] = hi; p[1] = lo;
    for (int k2 = 2; k2 < 32; ++k2) p[k2] = 0;
}

__global__ void prep_b_k(const float* __restrict__ e, unsigned short* __restrict__ Bh) {
    __shared__ float t[32][33];
    int jb = blockIdx.x * 32, db = blockIdx.y * 32;
#pragma unroll
    for (int i = 0; i < 4; ++i)
        t[threadIdx.y + i * 8][threadIdx.x] =
            e[(size_t)(db + threadIdx.y + i * 8) * NC + jb + threadIdx.x];
    __syncthreads();
#pragma unroll
    for (int i = 0; i < 4; ++i) {
        int j = jb + threadIdx.y + i * 8;
        int d = db + threadIdx.x;
        float val = t[threadIdx.x][threadIdx.y + i * 8];
        Bh[(size_t)j * BST + d]       = f2hb(val);
        Bh[(size_t)j * BST + 288 + d] = f2hb(val - (float)(_Float16)val);
    }
}

// ======================= R10 cheap kernel: A LDS-resident, 8 waves, swizzled =======================
// Block = 512 threads (8 waves, 2/SIMD for TLP). 128 rows x 2048 cols (js 4-way).
// A-hi (64 KB) + cHalf+BIAS (8 KB) in LDS once; B streams 16 KB/chunk (dbuf).
// SWIZZLE: LDS granule g of row r holds global k-granule (g&3)^s(r),
// s(r)=(r&3)^((r>>2)&3) -> fragment reads spread 16 l15-lanes over 8 banks
// (2-way = free) instead of 2 banks (8-way). s(r) invariant under r+64/128,
// so one per-thread ks serves all staged row groups. Store side unchanged
// (global source per-lane; LDS dst = tid*16B as global_load_lds requires).
// Wave tile 64x64: wr=(wave>>2)*64, wc=(wave&3)*64; 4-way col merge via LDS.

__global__ __launch_bounds__(512, 2) void vq_cheap_k(
    const unsigned short* __restrict__ Ah, const unsigned short* __restrict__ Bh,
    const float* __restrict__ cHalf,
    float* __restrict__ pv, int* __restrict__ pj, float* __restrict__ psv)
{
    __shared__ __align__(16) _Float16 Asl[8][4096];   // 64 KB [chunk][row*32 + swz granule*8]
    __shared__ __align__(16) _Float16 Bsl[2][8192];   // 32 KB [buf][col*32 + swz granule*8]
    __shared__ float chl[2048];                       //  8 KB

    const int tid  = threadIdx.x;
    const int js   = blockIdx.x & 3;
    const int rb   = blockIdx.x >> 2;
    const int row0 = rb * 128, col0 = js * 2048;
    const int lane = tid & 63, l15 = lane & 15, lq = lane >> 4;
    const int wave = tid >> 6;                 // 0..7
    const int wr = (wave >> 2) * 64;           // 0 / 64
    const int wc = (wave & 3) * 64;            // 0 / 64 / 128 / 192
    const int sr = tid >> 2;                   // staging row 0..127
    const int ks = (((tid & 3) ^ (sr & 3) ^ ((sr >> 2) & 3))) * 8;  // swizzled global k-offset

    // ---- prologue: A-hi -> LDS (one inst per chunk), cHalf+BIAS -> LDS ----
    const unsigned short* Abase = Ah + (size_t)(row0 + sr) * AST + ks;
#pragma unroll
    for (int c = 0; c < 8; ++c)
        __builtin_amdgcn_global_load_lds((gas_p)(Abase + c * 32), (las_p)&Asl[c][tid * 8], 16, 0, 0);
    {
        float4 a = ((const float4*)(cHalf + col0))[tid];
        a.x += BIAS; a.y += BIAS; a.z += BIAS; a.w += BIAS;
        ((float4*)chl)[tid] = a;
    }

#define LOADB(JT_, C_, BUF_)                                                                  \
    do {                                                                                      \
        const unsigned short* bb_ = Bh + (size_t)(col0 + (JT_) * 256 + sr) * BST + (C_) * 32 + ks; \
        _Float16* lb_ = &Bsl[(BUF_)][tid * 8];                                                \
        __builtin_amdgcn_global_load_lds((gas_p)bb_,               (las_p)lb_,          16, 0, 0); \
        __builtin_amdgcn_global_load_lds((gas_p)(bb_ + 128 * BST), (las_p)(lb_ + 4096), 16, 0, 0); \
    } while (0)

    unsigned k1[16], k2[16];
#pragma unroll
    for (int s = 0; s < 16; ++s) { k1[s] = 0xFFFFFFFFu; k2[s] = 0xFFFFFFFFu; }

    const floatx4 fzero = {0.0f, 0.0f, 0.0f, 0.0f};
    floatx4 acc[4][4];
#pragma unroll
    for (int rf = 0; rf < 4; ++rf)
#pragma unroll
        for (int cf = 0; cf < 4; ++cf) acc[rf][cf] = fzero;

    LOADB(0, 0, 0);

    for (int jt = 0; jt < 8; ++jt) {
#pragma unroll
        for (int c = 0; c < 8; ++c) {
            const int buf = c & 1;
            __syncthreads();                     // waits chunk c's B (issued 1 step ago) (+A/chl first time)
            if (c < 7)           LOADB(jt, c + 1, buf ^ 1);
            else if (jt < 7)     LOADB(jt + 1, 0, buf ^ 1);

            half8 af[4], bf[4];
#pragma unroll
            for (int rf = 0; rf < 4; ++rf) {
                const int m = wr + rf * 16 + l15;
                const int g = lq ^ (m & 3) ^ ((m >> 2) & 3);
                af[rf] = *(const half8*)&Asl[c][m * 32 + g * 8];
            }
#pragma unroll
            for (int cf = 0; cf < 4; ++cf) {
                const int n = wc + cf * 16 + l15;
                const int g = lq ^ (n & 3) ^ ((n >> 2) & 3);
                bf[cf] = *(const half8*)&Bsl[buf][n * 32 + g * 8];
            }
#pragma unroll
            for (int rf = 0; rf < 4; ++rf)
#pragma unroll
                for (int cf = 0; cf < 4; ++cf)
                    acc[rf][cf] = __builtin_amdgcn_mfma_f32_16x16x32_f16(
                        af[rf], bf[cf], acc[rf][cf], 0, 0, 0);

            if (c == 7) {
                // ---- per-jt epilogue (next jt's chunk-0 loads in flight) ----
#pragma unroll
                for (int cf = 0; cf < 4; ++cf) {
                    const unsigned colb = (unsigned)(jt * 256 + wc + cf * 16 + l15); // 11-bit local col
                    const float ch = chl[colb];
#pragma unroll
                    for (int rf = 0; rf < 4; ++rf)
#pragma unroll
                        for (int r = 0; r < 4; ++r) {
                            float s = acc[rf][cf][r] - ch;
                            unsigned key = (__float_as_uint(s) & 0xFFFFF800u) | colb;
                            int slot = rf * 4 + r;
                            unsigned t = umax_(key, k1[slot]);
                            k1[slot] = umin_(k1[slot], key);
                            k2[slot] = umin_(k2[slot], t);
                        }
                }
#pragma unroll
                for (int rf = 0; rf < 4; ++rf)
#pragma unroll
                    for (int cf = 0; cf < 4; ++cf) acc[rf][cf] = fzero;
            }
        }
    }
#undef LOADB

    // ---- cross-lane merge over the 16 l15-lanes of each row-group ----
#pragma unroll
    for (int st = 1; st < 16; st <<= 1) {
#pragma unroll
        for (int s = 0; s < 16; ++s) {
            unsigned o1 = (unsigned)__shfl_xor((int)k1[s], st, 64);
            unsigned o2 = (unsigned)__shfl_xor((int)k2[s], st, 64);
            unsigned t = umax_(k1[s], o1);
            k1[s] = umin_(k1[s], o1);
            k2[s] = umin_(umin_(k2[s], o2), t);
        }
    }

    // ---- merge the four column-group waves per row through LDS ----
    __syncthreads();
    unsigned* mk1 = (unsigned*)&Asl[0][0];       // [128 rows][4 col-groups]
    unsigned* mk2 = (unsigned*)&Asl[1][0];
    if (l15 == 0) {
#pragma unroll
        for (int rf = 0; rf < 4; ++rf)
#pragma unroll
            for (int r = 0; r < 4; ++r) {
                int rloc = wr + rf * 16 + lq * 4 + r;
                int slot = rf * 4 + r;
                mk1[rloc * 4 + (wave & 3)] = k1[slot];
                mk2[rloc * 4 + (wave & 3)] = k2[slot];
            }
    }
    __syncthreads();
    if (tid < 128) {
        unsigned a0 = mk1[tid * 4], a1 = mk1[tid * 4 + 1], a2 = mk1[tid * 4 + 2], a3 = mk1[tid * 4 + 3];
        unsigned x = umin_(a0, a1), y = umax_(a0, a1);
        unsigned z = umin_(a2, a3), w = umax_(a2, a3);
        unsigned m1  = umin_(x, z);
        unsigned sm1 = umin_(umax_(x, z), umin_(y, w));            // 2nd-best of the four bests
        unsigned s0 = mk2[tid * 4], s1 = mk2[tid * 4 + 1], s2 = mk2[tid * 4 + 2], s3 = mk2[tid * 4 + 3];
        unsigned m2 = umin_(umin_(umin_(s0, s1), umin_(s2, s3)), sm1);
        pv[(size_t)js * NROW + row0 + tid]  = __uint_as_float(m1 & 0xFFFFF800u);
        pj[(size_t)js * NROW + row0 + tid]  = (int)(m1 & 2047u) + js * 2048;
        psv[(size_t)js * NROW + row0 + tid] = __uint_as_float(m2 & 0xFFFFF800u);
    }
}

// ======================= rescue GEMM (R8-verified, unchanged) =======================

template<bool RESCUE>
static __device__ __forceinline__ void chunk_off(int c, int& ac, int& bc) {
    if constexpr (RESCUE) {
        if (c < 8)       { ac = c * 32;              bc = c * 32; }
        else if (c < 16) { ac = (c - 8) * 32;        bc = 288 + (c - 8) * 32; }
        else             { ac = 288 + (c - 16) * 32; bc = (c - 16) * 32; }
    } else {
        ac = c * 32; bc = c * 32;
    }
}

template<int CHUNKS, int JT, int JSB, bool RESCUE>
__global__ __launch_bounds__(256, 2) void vq_gemm_k(
    const unsigned short* __restrict__ Ah, const unsigned short* __restrict__ Bh,
    const float* __restrict__ cHalf,
    float* __restrict__ pv, int* __restrict__ pj, float* __restrict__ psv,
    const int* __restrict__ list, const int* __restrict__ cnt)
{
    __shared__ __align__(16) _Float16 As[2][4096];
    __shared__ __align__(16) _Float16 Bs[2][4096];

    const int tid  = threadIdx.x;
    const int js   = blockIdx.x & ((1 << JSB) - 1);
    const int rb   = blockIdx.x >> JSB;
    const int row0 = rb * 128, col0 = js * (JT * 128);
    const int lane = tid & 63, l15 = lane & 15, lq = lane >> 4;
    const int wave = tid >> 6;
    const int wrow = (wave >> 1) * 64, wcol = (wave & 1) * 64;
    const int sr = tid >> 2, sp = (tid & 3) * 8;

    int nact = 0;
    if constexpr (RESCUE) {
        nact = *cnt;
        if (row0 >= nact) return;
    }

    const unsigned short *Abase0, *Abase1;
    if constexpr (RESCUE) {
        int i0 = row0 + sr, i1 = i0 + 64;
        int r0 = (i0 < nact) ? list[i0] : 0;
        int r1 = (i1 < nact) ? list[i1] : 0;
        Abase0 = Ah + (size_t)r0 * AST + sp;
        Abase1 = Ah + (size_t)r1 * AST + sp;
    } else {
        Abase0 = Ah + (size_t)(row0 + sr) * AST + sp;
        Abase1 = Abase0 + 64 * AST;
    }

    unsigned k1[16], k2[16];
    float bvf[16]; int bjf[16];
#pragma unroll
    for (int s = 0; s < 16; ++s) {
        k1[s] = 0xFFFFFFFFu; k2[s] = 0xFFFFFFFFu;
        bvf[s] = -3.4e38f; bjf[s] = 0;
    }

    const floatx4 fzero = {0.0f, 0.0f, 0.0f, 0.0f};
    floatx4 acc[4][4];
#pragma unroll
    for (int rf = 0; rf < 4; ++rf)
#pragma unroll
        for (int cf = 0; cf < 4; ++cf) acc[rf][cf] = fzero;

    const unsigned short* Bb = Bh + (size_t)(col0 + sr) * BST + sp;

#define LOAD4(AC, BC, BUF, BBASE)                                                            \
    do {                                                                                     \
        _Float16* la_ = &As[(BUF)][tid * 8];                                                 \
        _Float16* lb_ = &Bs[(BUF)][tid * 8];                                                 \
        __builtin_amdgcn_global_load_lds((gas_p)(Abase0 + (AC)),            (las_p)la_,          16, 0, 0); \
        __builtin_amdgcn_global_load_lds((gas_p)(Abase1 + (AC)),            (las_p)(la_ + 2048), 16, 0, 0); \
        __builtin_amdgcn_global_load_lds((gas_p)((BBASE) + (BC)),           (las_p)lb_,          16, 0, 0); \
        __builtin_amdgcn_global_load_lds((gas_p)((BBASE) + 64 * BST + (BC)),(las_p)(lb_ + 2048), 16, 0, 0); \
    } while (0)

    LOAD4(0, 0, 0, Bb);

    for (int jt = 0; jt < JT; ++jt) {
        const int p = (CHUNKS & 1) ? (jt & 1) : 0;
#pragma unroll
        for (int c = 0; c < CHUNKS; ++c) {
            const int buf = (c & 1) ^ p;
            __syncthreads();
            if (c + 1 < CHUNKS) {
                int an, bn;
                chunk_off<RESCUE>(c + 1, an, bn);
                LOAD4(an, bn, buf ^ 1, Bb);
            } else if (jt + 1 < JT) {
                LOAD4(0, 0, buf ^ 1, Bb + 128 * BST);
            }

            half8 af[4], bf[4];
#pragma unroll
            for (int rf = 0; rf < 4; ++rf)
                af[rf] = *(const half8*)&As[buf][(wrow + rf * 16 + l15) * 32 + lq * 8];
#pragma unroll
            for (int cf = 0; cf < 4; ++cf)
                bf[cf] = *(const half8*)&Bs[buf][(wcol + cf * 16 + l15) * 32 + lq * 8];
#pragma unroll
            for (int rf = 0; rf < 4; ++rf)
#pragma unroll
                for (int cf = 0; cf < 4; ++cf)
                    acc[rf][cf] = __builtin_amdgcn_mfma_f32_16x16x32_f16(
                        af[rf], bf[cf], acc[rf][cf], 0, 0, 0);

            if (c == CHUNKS - 1) {
                if constexpr (RESCUE) {
                    const int colbase = col0 + jt * 128 + wcol;
#pragma unroll
                    for (int cf = 0; cf < 4; ++cf) {
                        const int col = colbase + cf * 16 + l15;
                        const float ch = cHalf[col];
#pragma unroll
                        for (int rf = 0; rf < 4; ++rf)
#pragma unroll
                            for (int r = 0; r < 4; ++r) {
                                float s = acc[rf][cf][r] - ch;
                                int slot = rf * 4 + r;
                                if (s > bvf[slot]) { bvf[slot] = s; bjf[slot] = col; }
                            }
                    }
                } else {
                    const unsigned colloc = (unsigned)(jt * 128 + wcol);
#pragma unroll
                    for (int cf = 0; cf < 4; ++cf) {
                        const unsigned colb = colloc + cf * 16 + l15;
#pragma unroll
                        for (int rf = 0; rf < 4; ++rf)
#pragma unroll
                            for (int r = 0; r < 4; ++r) {
                                unsigned key = (__float_as_uint(acc[rf][cf][r]) & 0xFFFFF800u) | colb;
                                int slot = rf * 4 + r;
                                unsigned t = umax_(key, k1[slot]);
                                k1[slot] = umin_(k1[slot], key);
                                k2[slot] = umin_(k2[slot], t);
                            }
                    }
                }
#pragma unroll
                for (int rf = 0; rf < 4; ++rf)
#pragma unroll
                    for (int cf = 0; cf < 4; ++cf) acc[rf][cf] = fzero;
            }
        }
        Bb += 128 * BST;
    }
#undef LOAD4

#pragma unroll
    for (int st = 1; st < 16; st <<= 1) {
#pragma unroll
        for (int s = 0; s < 16; ++s) {
            if constexpr (RESCUE) {
                float v2 = __shfl_xor(bvf[s], st, 64);
                int   j2 = __shfl_xor(bjf[s], st, 64);
                if (v2 > bvf[s] || (v2 == bvf[s] && j2 < bjf[s])) { bvf[s] = v2; bjf[s] = j2; }
            } else {
                unsigned o1 = (unsigned)__shfl_xor((int)k1[s], st, 64);
                unsigned o2 = (unsigned)__shfl_xor((int)k2[s], st, 64);
                unsigned t = umax_(k1[s], o1);
                k1[s] = umin_(k1[s], o1);
                k2[s] = umin_(umin_(k2[s], o2), t);
            }
        }
    }

    __syncthreads();
    if constexpr (RESCUE) {
        float* mv = (float*)&As[0][0];
        int*   mj = (int*)&Bs[0][0];
        if (l15 == 0) {
#pragma unroll
            for (int rf = 0; rf < 4; ++rf)
#pragma unroll
                for (int r = 0; r < 4; ++r) {
                    int rloc = wrow + rf * 16 + lq * 4 + r;
                    int slot = rf * 4 + r;
                    mv[rloc * 2 + (wave & 1)] = bvf[slot];
                    mj[rloc * 2 + (wave & 1)] = bjf[slot];
                }
        }
        __syncthreads();
        if (tid < 128) {
            float v0 = mv[tid * 2], v1 = mv[tid * 2 + 1];
            int   j0 = mj[tid * 2], j1 = mj[tid * 2 + 1];
            bool take1 = (v1 > v0) || (v1 == v0 && j1 < j0);
            pv[(size_t)js * CAP + row0 + tid] = take1 ? v1 : v0;
            pj[(size_t)js * CAP + row0 + tid] = take1 ? j1 : j0;
        }
    } else {
        unsigned* mk1 = (unsigned*)&As[0][0];
        unsigned* mk2 = (unsigned*)&Bs[0][0];
        if (l15 == 0) {
#pragma unroll
            for (int rf = 0; rf < 4; ++rf)
#pragma unroll
                for (int r = 0; r < 4; ++r) {
                    int rloc = wrow + rf * 16 + lq * 4 + r;
                    int slot = rf * 4 + r;
                    mk1[rloc * 2 + (wave & 1)] = k1[slot];
                    mk2[rloc * 2 + (wave & 1)] = k2[slot];
                }
        }
        __syncthreads();
        if (tid < 128) {
            unsigned a1 = mk1[tid * 2], b1 = mk1[tid * 2 + 1];
            unsigned a2 = mk2[tid * 2], b2 = mk2[tid * 2 + 1];
            unsigned m1 = umin_(a1, b1);
            unsigned m2 = umin_(umin_(a2, b2), umax_(a1, b1));
            pv[(size_t)js * NROW + row0 + tid] = __uint_as_float(m1 & 0xFFFFF800u);
            pj[(size_t)js * NROW + row0 + tid] = (int)(m1 & 2047u) + js * (JT * 128);
            psv[(size_t)js * NROW + row0 + tid] = __uint_as_float(m2 & 0xFFFFF800u);
        }
    }
}

// ======================= cheap reduce: merge splits, flag, gather =======================

__global__ void vq_reduce_k(const float* __restrict__ pv, const int* __restrict__ pj,
                            const float* __restrict__ psv,
                            const float* __restrict__ norms, const unsigned short* __restrict__ Bh,
                            float* __restrict__ qout, float* __restrict__ iout,
                            float* __restrict__ lout, int* __restrict__ list,
                            int* __restrict__ cnt)
{
    __shared__ int jbuf[64];
    const int row0 = blockIdx.x * 64;
    const int tid = threadIdx.x;
    if (tid < 64) {
        int row = row0 + tid;
        float bv = pv[row]; int bj = pj[row]; float sv = psv[row];
#pragma unroll
        for (int s = 1; s < 4; ++s) {
            float v = pv[(size_t)s * NROW + row];
            int   j = pj[(size_t)s * NROW + row];
            float s2 = psv[(size_t)s * NROW + row];
            bool better = (v > bv) || (v == bv && j < bj);
            float loseBest = better ? bv : v;
            sv = fmaxf(fmaxf(sv, s2), loseBest);
            if (better) { bv = v; bj = j; }
        }
        bool flagged = (bv - sv) < MARGINF;
        if (flagged) {
            int idx = atomicAdd(cnt, 1);
            if (idx < CAP) {
                list[idx] = row;
                jbuf[tid] = -1;
            } else {
                flagged = false;
            }
        }
        float rl = 0.f;
        if (!flagged) {
            iout[row] = (float)bj;
            jbuf[tid] = bj;
            rl = norms[row] - 2.0f * (bv + BIAS - 0.0625f);
        }
#pragma unroll
        for (int off = 32; off; off >>= 1) rl += __shfl_down(rl, off, 64);
        if (tid == 0) atomicAdd(lout, rl * LOSS_SCALE);
    }
    __syncthreads();
    const int lane = tid & 63;
    for (int r = tid >> 6; r < 64; r += 4) {
        int j = jbuf[r];
        if (j >= 0) {
            const _Float16* bp = (const _Float16*)Bh + (size_t)j * BST + lane * 4;
            half4 h = *(const half4*)bp;
            half4 l = *(const half4*)(bp + 288);
            float4 v;
            v.x = (float)h[0] + (float)l[0];
            v.y = (float)h[1] + (float)l[1];
            v.z = (float)h[2] + (float)l[2];
            v.w = (float)h[3] + (float)l[3];
            *(float4*)&qout[(size_t)(row0 + r) * DIM + lane * 4] = v;
        }
    }
}

// ======================= rescue reduce: merge 32 splits, finalize =======================

__global__ void vq_reduce2_k(const float* __restrict__ pv2, const int* __restrict__ pj2,
                             const int* __restrict__ list, const int* __restrict__ cnt,
                             const float* __restrict__ norms, const unsigned short* __restrict__ Bh,
                             float* __restrict__ qout, float* __restrict__ iout,
                             float* __restrict__ lout)
{
    __shared__ int rbuf[64], jb2[64];
    const int n = *cnt < CAP ? *cnt : CAP;
    const int i0 = blockIdx.x * 64;
    if (i0 >= n) return;
    const int tid = threadIdx.x;
    if (tid < 64) {
        int i = i0 + tid;
        float rl = 0.f;
        if (i < n) {
            float bv = pv2[i]; int bj = pj2[i];
#pragma unroll 4
            for (int s = 1; s < 32; ++s) {
                float v = pv2[(size_t)s * CAP + i];
                int   j = pj2[(size_t)s * CAP + i];
                if (v > bv || (v == bv && j < bj)) { bv = v; bj = j; }
            }
            int row = list[i];
            iout[row] = (float)bj;
            rbuf[tid] = row;
            jb2[tid]  = bj;
            rl = norms[row] - 2.0f * bv;
        } else {
            rbuf[tid] = -1;
        }
#pragma unroll
        for (int off = 32; off; off >>= 1) rl += __shfl_down(rl, off, 64);
        if (tid == 0) atomicAdd(lout, rl * LOSS_SCALE);
    }
    __syncthreads();
    const int lane = tid & 63;
    for (int r = tid >> 6; r < 64; r += 4) {
        int row = rbuf[r];
        if (row >= 0) {
            const _Float16* bp = (const _Float16*)Bh + (size_t)jb2[r] * BST + lane * 4;
            half4 h = *(const half4*)bp;
            half4 l = *(const half4*)(bp + 288);
            float4 v;
            v.x = (float)h[0] + (float)l[0];
            v.y = (float)h[1] + (float)l[1];
            v.z = (float)h[2] + (float)l[2];
            v.w = (float)h[3] + (float)l[3];
            *(float4*)&qout[(size_t)row * DIM + lane * 4] = v;
        }
    }
}

// ======================= fallback fp32 path (round-1, known-good) =======================

__global__ void transpose_k(const float* __restrict__ e, float* __restrict__ eT) {
    __shared__ float t[32][33];
    int jb = blockIdx.x * 32, db = blockIdx.y * 32;
#pragma unroll
    for (int i = 0; i < 4; ++i)
        t[threadIdx.y + i * 8][threadIdx.x] =
            e[(size_t)(db + threadIdx.y + i * 8) * NC + jb + threadIdx.x];
    __syncthreads();
#pragma unroll
    for (int i = 0; i < 4; ++i)
        eT[(size_t)(jb + threadIdx.y + i * 8) * DIM + db + threadIdx.x] =
            t[threadIdx.x][threadIdx.y + i * 8];
}

__global__ void row_norms_k(const float* __restrict__ x, float* __restrict__ norms) {
    int row  = blockIdx.x * 4 + (threadIdx.x >> 6);
    int lane = threadIdx.x & 63;
    const float4 v = ((const float4*)(x + (size_t)row * DIM))[lane];
    float s = v.x * v.x + v.y * v.y + v.z * v.z + v.w * v.w;
#pragma unroll
    for (int off = 32; off; off >>= 1) s += __shfl_down(s, off, 64);
    if (lane == 0) norms[row] = s;
}

__global__ void code_norms_fb_k(const float* __restrict__ e, float* __restrict__ cHalf) {
    int j = blockIdx.x * 256 + threadIdx.x;
    float s = 0.f;
    for (int d = 0; d < DIM; ++d) { float v = e[(size_t)d * NC + j]; s += v * v; }
    cHalf[j] = 0.5f * s;
}

__global__ __launch_bounds__(256, 4) void vq_main_k(
    const float* __restrict__ x, const float* __restrict__ e,
    const float* __restrict__ eT, const float* __restrict__ norms,
    const float* __restrict__ cHalf, float* __restrict__ qout,
    float* __restrict__ iout, float* __restrict__ lout, int useT)
{
    __shared__ float  As[2][32 * 68];
    __shared__ float4 Bs[2][512];
    const int tid  = threadIdx.x;
    const int row0 = blockIdx.x * 64;
    const int ty = tid >> 4, tx = tid & 15;
    const int ar = tid >> 2, ak = (tid & 3) * 4;
    const int bk = tid >> 4, bj = tid & 15;
    float bestv[4]; int bestj[4];
#pragma unroll
    for (int i = 0; i < 4; ++i) { bestv[i] = -3.4e38f; bestj[i] = 0; }
    float acc[4][4];
    float4 pa0, pa1, pb0, pb1;
    {
        const float* xp = x + (size_t)(row0 + ar) * DIM + ak;
        pa0 = *(const float4*)xp;
        pa1 = *(const float4*)(xp + 16);
        const float* ep = e + (size_t)bk * NC + bj * 4;
        pb0 = *(const float4*)ep;
        pb1 = *(const float4*)(ep + 16 * NC);
    }
    int buf = 0;
    for (int c = 0; c < 1024; ++c) {
        const int kc = c & 7;
#pragma unroll
        for (int q = 0; q < 4; ++q) As[buf][(ak + q) * 68 + ar]      = ((const float*)&pa0)[q];
#pragma unroll
        for (int q = 0; q < 4; ++q) As[buf][(16 + ak + q) * 68 + ar] = ((const float*)&pa1)[q];
        Bs[buf][bk * 16 + bj]        = pb0;
        Bs[buf][(bk + 16) * 16 + bj] = pb1;
        __syncthreads();
        if (c + 1 < 1024) {
            int j0n  = ((c + 1) >> 3) * 64;
            int kk0n = ((c + 1) & 7) * 32;
            const float* xp = x + (size_t)(row0 + ar) * DIM + kk0n + ak;
            pa0 = *(const float4*)xp;
            pa1 = *(const float4*)(xp + 16);
            const float* ep = e + (size_t)(kk0n + bk) * NC + j0n + bj * 4;
            pb0 = *(const float4*)ep;
            pb1 = *(const float4*)(ep + 16 * NC);
        }
        if (kc == 0) {
#pragma unroll
            for (int i = 0; i < 4; ++i)
#pragma unroll
                for (int j = 0; j < 4; ++j) acc[i][j] = 0.f;
        }
#pragma unroll
        for (int k = 0; k < 32; ++k) {
            float4 a = *(const float4*)&As[buf][k * 68 + ty * 4];
            float4 b = *(const float4*)&Bs[buf][k * 16 + tx];
            acc[0][0] += a.x * b.x; acc[0][1] += a.x * b.y; acc[0][2] += a.x * b.z; acc[0][3] += a.x * b.w;
            acc[1][0] += a.y * b.x; acc[1][1] += a.y * b.y; acc[1][2] += a.y * b.z; acc[1][3] += a.y * b.w;
            acc[2][0] += a.z * b.x; acc[2][1] += a.z * b.y; acc[2][2] += a.z * b.z; acc[2][3] += a.z * b.w;
            acc[3][0] += a.w * b.x; acc[3][1] += a.w * b.y; acc[3][2] += a.w * b.z; acc[3][3] += a.w * b.w;
        }
        if (kc == 7) {
            int j0 = (c >> 3) * 64;
            float4 ch = *(const float4*)&cHalf[j0 + tx * 4];
            int jb0 = j0 + tx * 4;
#pragma unroll
            for (int i = 0; i < 4; ++i)
#pragma unroll
                for (int j = 0; j < 4; ++j) {
                    float s = acc[i][j] - ((const float*)&ch)[j];
                    if (s > bestv[i]) { bestv[i] = s; bestj[i] = jb0 + j; }
                }
        }
        buf ^= 1;
    }
    __syncthreads();
    float* redv   = &As[0][0];
    int*   redj   = (int*)&As[0][1024];
    int*   idxbuf = (int*)&As[1][0];
#pragma unroll
    for (int i = 0; i < 4; ++i) {
        int r = ty * 4 + i;
        redv[r * 16 + tx] = bestv[i];
        redj[r * 16 + tx] = bestj[i];
    }
    __syncthreads();
    if (tid < 64) {
        float bvv = redv[tid * 16];
        int   bj2 = redj[tid * 16];
#pragma unroll
        for (int t = 1; t < 16; ++t) {
            float v = redv[tid * 16 + t];
            int   j = redj[tid * 16 + t];
            if (v > bvv || (v == bvv && j < bj2)) { bvv = v; bj2 = j; }
        }
        iout[row0 + tid] = (float)bj2;
        idxbuf[tid] = bj2;
        float rl = norms[row0 + tid] - 2.0f * bvv;
#pragma unroll
        for (int off = 32; off; off >>= 1) rl += __shfl_down(rl, off, 64);
        if (tid == 0) atomicAdd(lout, rl * LOSS_SCALE);
    }
    __syncthreads();
    {
        const int rr = tid >> 6, lane = tid & 63;
        for (int r = rr; r < 64; r += 4) {
            int j = idxbuf[r];
            float4 v;
            if (useT) {
                v = *(const float4*)&eT[(size_t)j * DIM + lane * 4];
            } else {
                int d = lane * 4;
                v.x = e[(size_t)d * NC + j];
                v.y = e[(size_t)(d + 1) * NC + j];
                v.z = e[(size_t)(d + 2) * NC + j];
                v.w = e[(size_t)(d + 3) * NC + j];
            }
            *(float4*)&qout[(size_t)(row0 + r) * DIM + lane * 4] = v;
        }
    }
}

// ======================= launch =======================

extern "C" void kernel_launch(void* const* d_in, const int* in_sizes, int n_in,
                              void* d_out, int out_size, void* d_ws, size_t ws_size,
                              hipStream_t stream) {
    const float* x = (const float*)d_in[0];   // [32768, 256]
    const float* e = (const float*)d_in[1];   // [256, 8192]

    float* qout = (float*)d_out;
    float* iout = qout + (size_t)NROW * DIM;
    float* lout = iout + NROW;

    char* ws = (char*)d_ws;
    const size_t offAh    = 0;                    // 32768*576*2 = 37,748,736
    const size_t offBh    = offAh + 37748736;     //  8192*576*2 =  9,437,184
    const size_t offNorms = offBh + 9437184;      //    131,072
    const size_t offCH    = offNorms + 131072;    //     32,768
    const size_t offPV    = offCH + 32768;        //    524,288
    const size_t offPJ    = offPV + 524288;       //    524,288
    const size_t offPSV   = offPJ + 524288;       //    524,288
    const size_t offPV2   = offPSV + 524288;      //  2,097,152
    const size_t offPJ2   = offPV2 + 2097152;     //  2,097,152
    const size_t offList  = offPJ2 + 2097152;     //     65,536
    const size_t offCnt   = offList + 65536;      //        256
    const size_t needFast = offCnt + 256;         // ~53.2 MB (proven: >=55.7 MB available)

    hipMemsetAsync(lout, 0, sizeof(float), stream);

    if (ws_size >= needFast) {
        unsigned short* Ah = (unsigned short*)(ws + offAh);
        unsigned short* Bh = (unsigned short*)(ws + offBh);
        float* norms = (float*)(ws + offNorms);
        float* cHalf = (float*)(ws + offCH);
        float* pv    = (float*)(ws + offPV);
        int*   pj    = (int*)(ws + offPJ);
        float* psv   = (float*)(ws + offPSV);
        float* pv2   = (float*)(ws + offPV2);
        int*   pj2   = (int*)(ws + offPJ2);
        int*   list  = (int*)(ws + offList);
        int*   cnt   = (int*)(ws + offCnt);

        hipMemsetAsync(cnt, 0, sizeof(int), stream);
        prep_a_k<<<NROW / 4, 256, 0, stream>>>(x, Ah, norms);
        code_norms_k<<<NC / 256, 256, 0, stream>>>(e, Bh, cHalf);
        prep_b_k<<<dim3(NC / 32, DIM / 32), dim3(32, 8), 0, stream>>>(e, Bh);
        // cheap pass (R10): A-resident LDS, 8 waves, swizzled banks
        vq_cheap_k<<<1024, 512, 0, stream>>>(Ah, Bh, cHalf, pv, pj, psv);
        // merge + flag + finalize non-flagged
        vq_reduce_k<<<NROW / 64, 256, 0, stream>>>(
            pv, pj, psv, norms, Bh, qout, iout, lout, list, cnt);
        // precise pass (K=768, exact fp32 cHalf) on flagged rows: 32 col-splits of 256
        vq_gemm_k<24, 2, 5, true><<<(CAP / 128) * 32, 256, 0, stream>>>(
            Ah, Bh, cHalf, pv2, pj2, nullptr, list, cnt);
        vq_reduce2_k<<<CAP / 64, 256, 0, stream>>>(
            pv2, pj2, list, cnt, norms, Bh, qout, iout, lout);
    } else {
        // round-1 fp32 fallback
        float* fws   = (float*)d_ws;
        float* norms = fws;
        float* cHalf = fws + NROW;
        float* eT    = fws + NROW + NC;
        size_t need_T = (size_t)(NROW + NC) * sizeof(float) + (size_t)NC * DIM * sizeof(float);
        int useT = (ws_size >= need_T) ? 1 : 0;
        row_norms_k<<<NROW / 4, 256, 0, stream>>>(x, norms);
        code_norms_fb_k<<<NC / 256, 256, 0, stream>>>(e, cHalf);
        if (useT)
            transpose_k<<<dim3(NC / 32, DIM / 32), dim3(32, 8), 0, stream>>>(e, eT);
        vq_main_k<<<NROW / 64, 256, 0, stream>>>(x, e, eT, norms, cHalf, qout, iout, lout, useT);
    }
}